// Round 5
// baseline (2030.323 us; speedup 1.0000x reference)
//
#include <hip/hip_runtime.h>
#include <math.h>

// Problem dims: B=256, T=64, N=128, M=256, P=256, YD=1
// 256 blocks x 512 threads. Group = 16 blocks = 16 batches; block role mt = m-tile.
// Wave specialization: waves 0-3 attention || waves 4-7 h-GEMM, per step.
// R5 = R4 + S accumulation via PER-BLOCK PARTIAL STORES instead of cross-block
// atomics (encoder S and decoder Sd). Producers store partial[batch][j][mt]
// (private slot, no RMW -> bar_arrive's vmcnt(0) drain shortens); consumers sum
// 16 partials at S-read (enc: 1 float4/lane + 2 shfl; dec: 4 float4/lane).
// Loads are one-shot, barrier-ordered: NO polling (avoids R1's retry flood).
// S zero-phases deleted (overwrite semantics). Barrier protocol unchanged except
// ONE extra group barrier pre-decoder (covers DP[0] zeroing visibility).
// Partials live in dead, group-local workspace:
//   EP (encoder): group's XeWt slice, [grp]*262144 + parity*16384 + bl*1024 + j*16 + mt
//       (dead until P2; parity 0 zeroed by darnn_init)
//   DP (decoder): group's XWt slice,  [grp]*131072 + parity*65536 + bl*4096 + j*16 + mt
//       (dead after xwreg hoist; parity 0 zeroed pre-decoder behind the extra barrier)

// Workspace layout (float offsets)
#define OFF_XWT   0u
#define OFF_XEWT  2097152u
#define OFF_XE    6291456u
#define OFF_HE    10485760u   // [2][16][256][16] h_e transposed [buf][grp][k][bl]
#define OFF_HD    10616832u
#define OFF_SB    10747904u   // yt channel only: parity-1 rows' slots 0,1
#define OFF_SDB   10780672u   // (unused in this rev)
#define OFF_XA    10911744u   // [16][128][16]
#define OFF_CTX   10944512u
#define OFF_YT    11010048u   // (unused in this rev)
#define OFF_BAR   11010304u
#define WS_END    11010816u

#define SENT_U 0x7FC00001u

// LDS: SLAB | PER | SCR | FLG
#define SLAB_F 24576
#define PER_F  2432
#define SCR_F  12288
#define FLG_F  16
#define SMEM_F (SLAB_F + PER_F + SCR_F + FLG_F)
#define SMEM_BYTES (SMEM_F * 4)   // 157248 <= 160 KB

#define F_E 0
#define F_L 1
#define F_B 2

__device__ __forceinline__ float fast_tanh(float x) {
  float xc = fminf(15.f, fmaxf(-15.f, x));
  float e = __expf(2.f * xc);
  return 1.f - 2.f * __builtin_amdgcn_rcpf(e + 1.f);
}
__device__ __forceinline__ float fast_sig(float x) {
  float xc = fminf(30.f, fmaxf(-30.f, x));
  return __builtin_amdgcn_rcpf(1.f + __expf(-xc));
}
__device__ __forceinline__ float wave_max(float v) {
#pragma unroll
  for (int o = 32; o; o >>= 1) v = fmaxf(v, __shfl_xor(v, o));
  return v;
}
__device__ __forceinline__ float wave_sum(float v) {
#pragma unroll
  for (int o = 32; o; o >>= 1) v += __shfl_xor(v, o);
  return v;
}
__device__ __forceinline__ float dot4(float4 a, float4 b) {
  return a.x*b.x + a.y*b.y + a.z*b.z + a.w*b.w;
}

// ---- device-scope (sc1) helpers; float4 only as ASM OUTPUT ----
__device__ __forceinline__ void st1_sc1(float* p, float v) {
  asm volatile("global_store_dword %0, %1, off sc1" :: "v"(p), "v"(v) : "memory");
}
__device__ __forceinline__ void ld1q_sc1(float4& a, const float* pa) {
  asm volatile("global_load_dwordx4 %0, %1, off sc1\n\ts_waitcnt vmcnt(0)"
               : "=&v"(a) : "v"(pa) : "memory");
}
__device__ __forceinline__ void ld1q_nw(float4& a, const float* pa) {
  asm volatile("global_load_dwordx4 %0, %1, off sc1"
               : "=&v"(a) : "v"(pa) : "memory");
}
__device__ __forceinline__ void vm0() {
  asm volatile("s_waitcnt vmcnt(0)" ::: "memory");
}
__device__ __forceinline__ void lgk0() {
  asm volatile("s_waitcnt lgkmcnt(0)" ::: "memory");
}
__device__ __forceinline__ float ld1s_sc1(const float* p) {
  float v;
  asm volatile("global_load_dword %0, %1, off sc1\n\ts_waitcnt vmcnt(0)"
               : "=&v"(v) : "v"(p) : "memory");
  return v;
}
__device__ __forceinline__ void ld8s_sc1(
    float& a0,float& a1,float& a2,float& a3,float& a4,float& a5,float& a6,float& a7,
    const float* p0,const float* p1,const float* p2,const float* p3,
    const float* p4,const float* p5,const float* p6,const float* p7) {
  asm volatile(
      "global_load_dword %0, %8, off sc1\n\t"
      "global_load_dword %1, %9, off sc1\n\t"
      "global_load_dword %2, %10, off sc1\n\t"
      "global_load_dword %3, %11, off sc1\n\t"
      "global_load_dword %4, %12, off sc1\n\t"
      "global_load_dword %5, %13, off sc1\n\t"
      "global_load_dword %6, %14, off sc1\n\t"
      "global_load_dword %7, %15, off sc1\n\t"
      "s_waitcnt vmcnt(0)"
      : "=&v"(a0),"=&v"(a1),"=&v"(a2),"=&v"(a3),
        "=&v"(a4),"=&v"(a5),"=&v"(a6),"=&v"(a7)
      : "v"(p0),"v"(p1),"v"(p2),"v"(p3),"v"(p4),"v"(p5),"v"(p6),"v"(p7)
      : "memory");
}

// LDS flag sync (monotonic counters; subset-of-waves sync without s_barrier)
__device__ __forceinline__ void lds_inc(unsigned* f) {
  __hip_atomic_fetch_add(f, 1u, __ATOMIC_RELAXED, __HIP_MEMORY_SCOPE_WORKGROUP);
}
__device__ __forceinline__ void lds_poll(unsigned* f, unsigned tgt) {
  unsigned cur;
  do { cur = __hip_atomic_load(f, __ATOMIC_RELAXED, __HIP_MEMORY_SCOPE_WORKGROUP); } while (cur < tgt);
  asm volatile("" ::: "memory");
}

#define FMA16V(a0,a1,a2,a3,xv,wv) \
  a0.x += xv.x*wv.x; a0.y += xv.x*wv.y; a0.z += xv.x*wv.z; a0.w += xv.x*wv.w; \
  a1.x += xv.y*wv.x; a1.y += xv.y*wv.y; a1.z += xv.y*wv.z; a1.w += xv.y*wv.w; \
  a2.x += xv.z*wv.x; a2.y += xv.z*wv.y; a2.z += xv.z*wv.z; a2.w += xv.z*wv.w; \
  a3.x += xv.w*wv.x; a3.y += xv.w*wv.y; a3.z += xv.w*wv.z; a3.w += xv.w*wv.w;

// Split fence-free group barrier (monotonic counter, relaxed agent atomics)
__device__ __forceinline__ void bar_arrive(unsigned* bar) {
  asm volatile("s_waitcnt vmcnt(0)" ::: "memory");
  __syncthreads();
  if (threadIdx.x == 0)
    __hip_atomic_fetch_add(bar, 1u, __ATOMIC_RELAXED, __HIP_MEMORY_SCOPE_AGENT);
}
__device__ __forceinline__ void bar_wait(unsigned* bar, unsigned target) {
  if (threadIdx.x == 0) {
    unsigned cur;
    do {
      __builtin_amdgcn_s_sleep(1);   // backoff: avoid IC poll livelock
      cur = __hip_atomic_load(bar, __ATOMIC_RELAXED, __HIP_MEMORY_SCOPE_AGENT);
    } while (cur < target);
  }
  __syncthreads();
}

__global__ void darnn_init(float* __restrict__ ws, float* __restrict__ out) {
  unsigned i = blockIdx.x * 256u + threadIdx.x;
  const unsigned span = WS_END - OFF_HE;
  for (unsigned idx = i; idx < span; idx += gridDim.x * 256u) ws[OFF_HE + idx] = 0.f;
  // zero EP[0] (encoder S-partials, parity 0) in each group's XeWt slice
  for (unsigned idx = i; idx < 262144u; idx += gridDim.x * 256u) {
    unsigned g = idx >> 14, off = idx & 16383u;
    ws[OFF_XEWT + g * 262144u + off] = 0.f;
  }
  if (i < 256u) out[i] = 0.f;
}

__global__ __launch_bounds__(512, 2) void darnn_main(
    const float* __restrict__ in,   const float* __restrict__ WUe,   const float* __restrict__ ve,
    const float* __restrict__ Wih_e,const float* __restrict__ Whh_e,
    const float* __restrict__ bih_e,const float* __restrict__ bhh_e,
    const float* __restrict__ WUd,  const float* __restrict__ vd,
    const float* __restrict__ wbt,  const float* __restrict__ Wih_d,
    const float* __restrict__ Whh_d,const float* __restrict__ bih_d, const float* __restrict__ bhh_d,
    const float* __restrict__ WbW,  const float* __restrict__ Wbb,
    const float* __restrict__ vbW,  const float* __restrict__ vbb,
    float* __restrict__ ws, float* __restrict__ out)
{
  extern __shared__ __align__(16) float sm[];
  float* SLAB = sm;
  float* PER  = sm + SLAB_F;
  float* SCR  = sm + SLAB_F + PER_F;
  unsigned* FLG = (unsigned*)(sm + SLAB_F + PER_F + SCR_F);
  const int tid = threadIdx.x;
  const int bid = blockIdx.x;
  const int grp = bid >> 4;
  const int mt  = bid & 15;
  const int b0  = grp << 4;
  const float SENTF = __uint_as_float(SENT_U);

  float* XWt  = ws + OFF_XWT;
  float* XeWt = ws + OFF_XEWT;
  float* Xe   = ws + OFF_XE;
  // partial-slot bases
  float* EP = ws + OFF_XEWT + (unsigned)grp * 262144u;  // [2][16][64][16]
  float* DP = ws + OFF_XWT  + (unsigned)grp * 131072u;  // [2][16][256][16]
  unsigned* barp = (unsigned*)(ws + OFF_BAR) + grp * 32;
  unsigned barn = 0;

  if (tid < FLG_F) FLG[tid] = 0u;

  // PER (encoder): wue_s [64][36]; ve_s @2304; bsum_e @2368
  float* wue_s  = PER;
  float* ve_s   = PER + 2304;
  float* bsum_e = PER + 2368;

  // rotated S-row for this thread's partial sweep (legacy rotation; harmless)
  const int jfixE = ((tid & 63) + mt * 4) & 63;

  // ---- one-time encoder staging ----
  {
    int r = tid & 63, kq = tid >> 6;
    int grow = (r & 3) * 256 + mt * 16 + (r >> 2);
#pragma unroll 4
    for (int q = 0; q < 12; ++q) {
      int k = kq * 48 + q * 4;
      float4 wv = (k < 128) ? *(const float4*)(Wih_e + grow * 128 + k)
                            : *(const float4*)(Whh_e + grow * 256 + (k - 128));
      SLAB[(k + 0) * 64 + r] = wv.x; SLAB[(k + 1) * 64 + r] = wv.y;
      SLAB[(k + 2) * 64 + r] = wv.z; SLAB[(k + 3) * 64 + r] = wv.w;
    }
    {
      int lin = tid * 4;
      int j = lin >> 5, c0 = lin & 31;
      int col = (c0 < 16) ? (mt * 16 + c0) : (256 + mt * 16 + (c0 - 16));
      float4 wv = *(const float4*)(WUe + j * 576 + col);
      *(float4*)(wue_s + j * 36 + c0) = wv;
    }
    if (tid < 64) {
      ve_s[tid] = ve[tid];
      int g = tid >> 4, m2 = tid & 15, m = mt * 16 + m2;
      bsum_e[tid] = bih_e[g * 256 + m] + bhh_e[g * 256 + m];
    }
  }

  // ---------------- P1: XWt[bid][j][n] = sum_k X[bid][k][n] * WU_e[j][512+k]
  {
    float* Xs = SCR;  // [128][68]
    const float* Xb = in + bid * 8256;
    __syncthreads();
    for (int it = 0; it < 16; ++it) {
      int lin = tid + it * 512;
      int k = lin >> 7, n = lin & 127;
      Xs[n * 68 + k] = Xb[k * 129 + n];
    }
    __syncthreads();
    int j = tid & 63, nh = tid >> 6;
    float acc[16];
#pragma unroll
    for (int i = 0; i < 16; ++i) acc[i] = 0.f;
    const float* wrow = WUe + j * 576 + 512;
    for (int kc = 0; kc < 4; ++kc) {
      float4 w0 = *(const float4*)(wrow + kc * 16 + 0);
      float4 w1 = *(const float4*)(wrow + kc * 16 + 4);
      float4 w2 = *(const float4*)(wrow + kc * 16 + 8);
      float4 w3 = *(const float4*)(wrow + kc * 16 + 12);
#pragma unroll
      for (int ni = 0; ni < 16; ++ni) {
        const float* xp = Xs + (nh * 16 + ni) * 68 + kc * 16;
        acc[ni] += dot4(*(const float4*)(xp + 0),  w0) + dot4(*(const float4*)(xp + 4),  w1)
                 + dot4(*(const float4*)(xp + 8),  w2) + dot4(*(const float4*)(xp + 12), w3);
      }
    }
    float* dst = XWt + bid * 8192 + j * 128 + nh * 16;
#pragma unroll
    for (int ni = 0; ni < 16; ++ni) dst[ni] = acc[ni];
    __syncthreads();
  }

  // hoist regs (constant over t); whc holds weights for ROTATED row jfixE
  float4 whc[8];
#pragma unroll
  for (int q = 0; q < 8; ++q) whc[q] = *(const float4*)(wue_s + jfixE * 36 + q * 4);
  float4 bsE = {0,0,0,0};
  {
    int m2 = tid & 15;
    bsE.x = bsum_e[m2]; bsE.y = bsum_e[16 + m2];
    bsE.z = bsum_e[32 + m2]; bsE.w = bsum_e[48 + m2];
  }
  // xwreg: wave w (0-3), lane l: n in {l, l+64}, j in w*16..+15
  float xwreg[32];
  if (tid < 256) {
    int w = tid >> 6, l = tid & 63;
    const float* xwp = XWt + bid * 8192;
#pragma unroll
    for (int jj = 0; jj < 16; ++jj) {
      xwreg[jj]      = xwp[(w * 16 + jj) * 128 + l];
      xwreg[16 + jj] = xwp[(w * 16 + jj) * 128 + 64 + l];
    }
  }
  float c_reg = 0.f;

  // ================ ENCODER: 64 steps ================
  for (int t = 0; t < 64; ++t) {
    const int rd = t & 1, wr2 = (t + 1) & 1;
    float* xah = SCR + 1024;     // [384][20]
    const int ks = tid >> 6, ml = (tid >> 2) & 15, b4 = tid & 3;
    float4 a0 = {0,0,0,0}, a1 = {0,0,0,0}, a2 = {0,0,0,0}, a3 = {0,0,0,0};

    bar_wait(barp, barn);        // EP(rd), h(rd) visible

    if (tid < 256) {
      // ---- attention (waves 0-3), arrives event B at the end (wave 0)
      int w = tid >> 6, l = tid & 63;
      float* Sj = SCR;           // [64]
      float* Ep = SCR + 64;      // [4][128]
      {  // gather S partials: lane handles j = w*16+(l&15), quarter q = l>>4
        int jj0 = l & 15, q = l >> 4;
        float4 pq;
        ld1q_sc1(pq, EP + (unsigned)rd * 16384u + (unsigned)mt * 1024u
                        + (unsigned)(w * 16 + jj0) * 16u + (unsigned)(q * 4));
        float ps = pq.x + pq.y + pq.z + pq.w;
        ps += __shfl_xor(ps, 16);
        ps += __shfl_xor(ps, 32);
        if (l < 16) Sj[w * 16 + l] = ps;
        lgk0();
      }
      float e0 = 0.f, e1 = 0.f;
#pragma unroll
      for (int jj = 0; jj < 16; ++jj) {
        float s = Sj[w * 16 + jj];
        float vv = ve_s[w * 16 + jj];
        e0 += vv * fast_tanh(xwreg[jj] + s);
        e1 += vv * fast_tanh(xwreg[16 + jj] + s);
      }
      Ep[w * 128 + l] = e0;
      Ep[w * 128 + 64 + l] = e1;
      lgk0();
      if (l == 0) lds_inc(FLG + F_E);
      if (w == 0) {
        lds_poll(FLG + F_E, 4u * (t + 1));
        float En0 = Ep[l] + Ep[128 + l] + Ep[256 + l] + Ep[384 + l];
        float En1 = Ep[64 + l] + Ep[192 + l] + Ep[320 + l] + Ep[448 + l];
        float mx = wave_max(fmaxf(En0, En1));
        float ex0 = __expf(En0 - mx), ex1 = __expf(En1 - mx);
        float tot = wave_sum(ex0 + ex1);
        float rt = __builtin_amdgcn_rcpf(tot);
        float x0 = in[bid * 8256 + t * 129 + l];
        float x1 = in[bid * 8256 + t * 129 + 64 + l];
        float* XAg = ws + OFF_XA + (unsigned)grp * 2048;
        st1_sc1(XAg + l * 16 + mt, x0 * ex0 * rt);
        st1_sc1(XAg + (64 + l) * 16 + mt, x1 * ex1 * rt);
        vm0();
        if (tid == 0)
          __hip_atomic_fetch_add(barp, 1u, __ATOMIC_RELAXED, __HIP_MEMORY_SCOPE_AGENT);
      }
    } else {
      // ---- h-part GEMM (waves 4-7): k in [128,384)
      int u = tid - 256;
      float4 h0, h1, h2, h3;
      const float* hb = ws + OFF_HE + (unsigned)rd * 65536 + (unsigned)grp * 4096 + u * 16;
      ld1q_nw(h0, hb); ld1q_nw(h1, hb + 4); ld1q_nw(h2, hb + 8); ld1q_nw(h3, hb + 12);
      vm0();
      float* row = xah + (unsigned)(128 + u) * 20;
      *(float4*)(row + 0) = h0; *(float4*)(row + 4) = h1;
      *(float4*)(row + 8) = h2; *(float4*)(row + 12) = h3;
      lgk0();
      int s = u >> 6;
      const float* xp = xah + (unsigned)(128 + s * 64) * 20 + b4 * 4;
      const float* wp = SLAB + (unsigned)(128 + s * 64) * 64 + ml * 4;
#pragma unroll 8
      for (int kk = 0; kk < 64; ++kk) {
        float4 xv = *(const float4*)(xp + kk * 20);
        float4 wv = *(const float4*)(wp + kk * 64);
        FMA16V(a0, a1, a2, a3, xv, wv);
      }
    }
    barn += 16;
    bar_wait(barp, barn);        // all XAs visible (internal sync rejoins waves)

    // plant decoder yt-channel sentinels once (parity-1 slots 0,1); drains at arrive
    if (t == 63 && tid == 0) {
      float* sp = ws + OFF_SB + 16384u + (unsigned)bid * 64u;
      st1_sc1(sp + 0, SENTF); st1_sc1(sp + 1, SENTF);
    }
    {  // per-wave XA staging: wave ks stages exactly rows ks*16..+15 it consumes
      int l = tid & 63;
      int k = (ks << 4) + (l >> 2), i4 = (l & 3) * 4;
      float4 q;
      ld1q_sc1(q, ws + OFF_XA + (unsigned)grp * 2048 + k * 16 + i4);
      *(float4*)(xah + k * 20 + i4) = q;
      lgk0();                    // wave-local: no block sync needed
    }
    {  // x-part: 8 strips x 16 k
      const float* xp = xah + (unsigned)(ks * 16) * 20 + b4 * 4;
      const float* wp = SLAB + (unsigned)(ks * 16) * 64 + ml * 4;
#pragma unroll 8
      for (int kk = 0; kk < 16; ++kk) {
        float4 xv = *(const float4*)(xp + kk * 20);
        float4 wv = *(const float4*)(wp + kk * 64);
        FMA16V(a0, a1, a2, a3, xv, wv);
      }
    }
    __syncthreads();             // xah dead -> red
    float* red = SCR;            // [512][20]
    {
      float* rp = red + (unsigned)(ks * 64 + ml * 4 + b4) * 20;
      *(float4*)(rp + 0) = a0; *(float4*)(rp + 4) = a1;
      *(float4*)(rp + 8) = a2; *(float4*)(rp + 12) = a3;
    }
    __syncthreads();
    float* hcs = SCR + 10240;    // [16][32]
    if (tid < 256) {
      int m2 = tid & 15, bl = tid >> 4;
      int t2 = m2 * 4 + (bl >> 2), bs = bl & 3;
      float4 gate = {0,0,0,0};
#pragma unroll
      for (int k2 = 0; k2 < 8; ++k2) {
        float4 rr = *(const float4*)(red + (unsigned)(k2 * 64 + t2) * 20 + bs * 4);
        gate.x += rr.x; gate.y += rr.y; gate.z += rr.z; gate.w += rr.w;
      }
      float gi = gate.x + bsE.x, gf = gate.y + bsE.y;
      float gg = gate.z + bsE.z, go = gate.w + bsE.w;
      float cn = fast_sig(gf) * c_reg + fast_sig(gi) * fast_tanh(gg);
      float hn = fast_sig(go) * fast_tanh(cn);
      c_reg = cn;
      unsigned m = mt * 16 + m2;
      st1_sc1(ws + OFF_HE + (unsigned)wr2 * 65536 + (unsigned)grp * 4096 + m * 16 + bl, hn);
      st1_sc1(Xe + ((unsigned)(b0 + bl) * 64 + t) * 256 + m, hn);
      hcs[bl * 32 + m2] = hn;
      hcs[bl * 32 + 16 + m2] = cn;
    }
    __syncthreads();
    {  // S partial STORES: 2 batches per thread, row jfixE, slot mt (no RMW)
      int wq = tid >> 6;
#pragma unroll
      for (int e2 = 0; e2 < 2; ++e2) {
        int bl2 = wq * 2 + e2;
        const float* hp = hcs + bl2 * 32;
        float s = 0.f;
#pragma unroll
        for (int q = 0; q < 4; ++q) {
          s += dot4(*(const float4*)(hp + q * 4), whc[q]);
          s += dot4(*(const float4*)(hp + 16 + q * 4), whc[4 + q]);
        }
        st1_sc1(EP + (unsigned)wr2 * 16384u + (unsigned)bl2 * 1024u
                   + (unsigned)jfixE * 16u + (unsigned)mt, s);
      }
    }
    barn += 16;
    bar_arrive(barp);
  }
  bar_wait(barp, barn);          // all Xe published

  // ---- fill Xe row into regs: tid<256, m = tid, all 64 t
  float xe[64];
  if (tid < 256) {
    const float* xb = Xe + (unsigned)bid * 16384 + tid;
#pragma unroll
    for (int g8 = 0; g8 < 8; ++g8) {
      ld8s_sc1(xe[g8*8+0], xe[g8*8+1], xe[g8*8+2], xe[g8*8+3],
               xe[g8*8+4], xe[g8*8+5], xe[g8*8+6], xe[g8*8+7],
               xb + (g8*8+0)*256, xb + (g8*8+1)*256, xb + (g8*8+2)*256,
               xb + (g8*8+3)*256, xb + (g8*8+4)*256, xb + (g8*8+5)*256,
               xb + (g8*8+6)*256, xb + (g8*8+7)*256);
    }
  }

  // ---- decoder one-time staging ----
  float* vd_s   = PER;
  float* wbt_s  = PER + 256;
  float* bsum_d = PER + 520;
  float* wihd_s = PER + 584;
  float* q_s    = PER + 704;      // [64] q[t'] = sum_m wbt[1+m]*Xe[b][t'][m]
  float* qpart  = PER + 768;      // [4][64] scratch
  float* wudT   = SLAB + 16384;   // [32][256]
  const int jfixD = ((tid & 255) + mt * 16) & 255;
  __syncthreads();
  {
    int r = tid & 63, kq = tid >> 6;
    int grow = (r & 3) * 256 + mt * 16 + (r >> 2);
#pragma unroll 4
    for (int q = 0; q < 8; ++q) {
      int k = kq * 32 + q * 4;
      float4 wv = *(const float4*)(Whh_d + grow * 256 + k);
      SLAB[(k + 0) * 64 + r] = wv.x; SLAB[(k + 1) * 64 + r] = wv.y;
      SLAB[(k + 2) * 64 + r] = wv.z; SLAB[(k + 3) * 64 + r] = wv.w;
    }
    {
      int j = tid & 255, half = tid >> 8;
#pragma unroll
      for (int i = 0; i < 16; ++i) {
        int c = half * 16 + i;
        int col = (c < 16) ? (mt * 16 + c) : (256 + mt * 16 + (c - 16));
        wudT[c * 256 + j] = WUd[(unsigned)j * 768 + col];
      }
    }
    if (tid < 256) vd_s[tid] = vd[tid];
    if (tid < 257) wbt_s[tid] = wbt[tid];
    if (tid < 64) {
      int g = tid >> 4, m2 = tid & 15, m = mt * 16 + m2;
      bsum_d[tid] = bih_d[g * 256 + m] + bhh_d[g * 256 + m];
      wihd_s[tid] = Wih_d[g * 256 + m];
    }
  }
  __syncthreads();

  // ---- q precompute: q[t'] = sum_m wbt[1+m] * Xe[b][t'][m]  (one-time)
  if (tid < 256) {
    int w = tid >> 6, l = tid & 63;
    float wm = wbt_s[1 + tid];
#pragma unroll
    for (int t4 = 0; t4 < 64; ++t4) {
      float v = wave_sum(wm * xe[t4]);
      if (l == 0) qpart[w * 64 + t4] = v;
    }
  }
  __syncthreads();
  if (tid < 64) q_s[tid] = qpart[tid] + qpart[64 + tid] + qpart[128 + tid] + qpart[192 + tid];
  __syncthreads();

  // ---------------- P2: XeWt[bid][j][t'] = sum_k Xe[bid][t'][k] * WU_d[j][512+k]
  // (overwrites EP region — EP is dead after the encoder)
  {
    float* XeT = SCR;          // [64][64]
    float* Wdc = SCR + 4096;   // [64][128]
    int tt2 = tid & 15, jq = tid >> 4;
    for (int jc = 0; jc < 2; ++jc) {
      float4 c0 = {0,0,0,0}, c1 = {0,0,0,0}, c2 = {0,0,0,0}, c3 = {0,0,0,0};
      for (int kc = 0; kc < 4; ++kc) {
        __syncthreads();
        if (tid < 256 && (tid >> 6) == kc) {
          int kk = tid & 63;
#pragma unroll
          for (int t4 = 0; t4 < 16; ++t4) {
            float4 v = { xe[t4*4+0], xe[t4*4+1], xe[t4*4+2], xe[t4*4+3] };
            *(float4*)(XeT + kk * 64 + t4 * 4) = v;
          }
        }
        {
          int jj = tid >> 2, k16 = (tid & 3) * 16;
          const float* src = WUd + (unsigned)(jc * 128 + jj) * 768 + 512 + kc * 64 + k16;
#pragma unroll
          for (int s4 = 0; s4 < 4; ++s4) {
            float4 wv = *(const float4*)(src + s4 * 4);
            Wdc[(k16 + s4*4 + 0) * 128 + jj] = wv.x;
            Wdc[(k16 + s4*4 + 1) * 128 + jj] = wv.y;
            Wdc[(k16 + s4*4 + 2) * 128 + jj] = wv.z;
            Wdc[(k16 + s4*4 + 3) * 128 + jj] = wv.w;
          }
        }
        __syncthreads();
#pragma unroll 8
        for (int kk = 0; kk < 64; ++kk) {
          float4 xv = *(const float4*)(XeT + kk * 64 + tt2 * 4);
          float4 wv = *(const float4*)(Wdc + kk * 128 + jq * 4);
          FMA16V(c0, c1, c2, c3, wv, xv);
        }
      }
      int jb = jc * 128 + jq * 4;
      *(float4*)(XeWt + ((unsigned)bid * 256 + jb + 0) * 64 + tt2 * 4) = c0;
      *(float4*)(XeWt + ((unsigned)bid * 256 + jb + 1) * 64 + tt2 * 4) = c1;
      *(float4*)(XeWt + ((unsigned)bid * 256 + jb + 2) * 64 + tt2 * 4) = c2;
      *(float4*)(XeWt + ((unsigned)bid * 256 + jb + 3) * 64 + tt2 * 4) = c3;
    }
    __syncthreads();
  }

  // hoist decoder regs; wreg for ROTATED row jfixD
  float wreg[32];
#pragma unroll
  for (int c = 0; c < 32; ++c) wreg[c] = wudT[c * 256 + jfixD];
  float4 bsD = {0,0,0,0}, wiD = {0,0,0,0};
  {
    int m2 = tid & 15;
    bsD.x = bsum_d[m2]; bsD.y = bsum_d[16 + m2]; bsD.z = bsum_d[32 + m2]; bsD.w = bsum_d[48 + m2];
    wiD.x = wihd_s[m2]; wiD.y = wihd_s[16 + m2]; wiD.z = wihd_s[32 + m2]; wiD.w = wihd_s[48 + m2];
  }
  // xewreg: wave w (0-3), lane l = t': j in w*64..+63
  float xewreg[64];
  if (tid < 256) {
    int w = tid >> 6, l = tid & 63;
    const float* xew = XeWt + (unsigned)bid * 16384 + l;
#pragma unroll
    for (int jj = 0; jj < 64; ++jj) xewreg[jj] = xew[(w * 64 + jj) << 6];
  }
  // wave0 per-lane hoists: q[l] and y-input y_t for t=l (shfl'd per step)
  float q_reg = 0.f, yv = 0.f;
  if (tid < 64) {
    q_reg = q_s[tid];
    if (tid < 63) yv = in[bid * 8256 + tid * 129 + 128];
  }
  const float wbt0 = wbt_s[0];
  float cd_reg = 0.f;

  // ---- zero DP[0] (decoder S-partials, parity 0), own bl=mt slice (4096 floats),
  //      then ONE extra group barrier so step-0 consumers see the zeros.
  //      (XWt region: dead after xwreg hoists; group-locked => no cross-group race)
  {
    float* dp0 = DP + (unsigned)mt * 4096u;
#pragma unroll
    for (int i8 = 0; i8 < 8; ++i8) st1_sc1(dp0 + (unsigned)(i8 * 512 + tid), 0.f);
    barn += 16;
    bar_arrive(barp);
  }

  // ================ DECODER: 63 steps ================
  // yt channel: slots 0/1 of SB parity-1 rows (sentineled at encoder t=63).
  // Barrier accounting: ONE bar_arrive (+16) per step; barn advances by 16.
  for (int t = 0; t < 63; ++t) {
    const int rd = t & 1, wr2 = (t + 1) & 1;
    const int ml = (tid >> 2) & 15, b4 = tid & 3;
    float* hT  = SCR + 2048;     // [256][20]
    float* red = SCR + 7168;     // [256][20]

    bar_wait(barp, barn);        // DP(rd), h(rd), yt-refill(rd from t-1) visible

    if (tid < 256) {
      // ---- attention (waves 0-3); wave0 publishes yt right after softmax (q-trick)
      int w = tid >> 6, l = tid & 63;
      float* Sdj  = SCR;         // [256]
      float* lp   = SCR + 256;   // [4][64]
      float* beta = SCR + 512;   // [64] (t==62 only)
      {  // gather Sd partials: lane handles j = w*64+l fully (16 partials)
        int j = w * 64 + l;
        const float* dpb = DP + (unsigned)rd * 65536u + (unsigned)mt * 4096u + (unsigned)j * 16u;
        float4 p0, p1, p2, p3;
        ld1q_nw(p0, dpb); ld1q_nw(p1, dpb + 4); ld1q_nw(p2, dpb + 8); ld1q_nw(p3, dpb + 12);
        vm0();
        Sdj[j] = (p0.x + p0.y + p0.z + p0.w) + (p1.x + p1.y + p1.z + p1.w)
               + (p2.x + p2.y + p2.z + p2.w) + (p3.x + p3.y + p3.z + p3.w);
        lgk0();
      }
      float lpar = 0.f;
#pragma unroll 8
      for (int jj = 0; jj < 64; ++jj)
        lpar += vd_s[w * 64 + jj] * fast_tanh(xewreg[jj] + Sdj[w * 64 + jj]);
      lp[w * 64 + l] = lpar;
      lgk0();
      if (l == 0) lds_inc(FLG + F_L);
      if (w == 0) {
        lds_poll(FLG + F_L, 4u * (t + 1));
        float lv = lp[l] + lp[64 + l] + lp[128 + l] + lp[192 + l];
        float mx = wave_max(lv);
        float ex = __expf(lv - mx);
        float sw = wave_sum(ex);
        float rt = __builtin_amdgcn_rcpf(sw);
        float ytn = wave_sum(ex * q_reg);
        if (l == 0) {
          float yt = wbt0 * __shfl(yv, t) + ytn * rt;
          st1_sc1(ws + OFF_SB + 16384u + (unsigned)bid * 64u + (unsigned)rd, yt);
        }
        // fire-and-forget: consumers sentinel-poll; drain happens at bar_arrive
        if (t == 62) {
          beta[l] = ex * rt;
          lgk0();
          if (l == 0) lds_inc(FLG + F_B);
        }
      }
      if (t == 62) {             // ctx only needed by FINAL
        lds_poll(FLG + F_B, 1u);
        lgk0();
        float ctx = 0.f;
#pragma unroll
        for (int tt = 0; tt < 64; ++tt) ctx += beta[tt] * xe[tt];
        st1_sc1(ws + OFF_CTX + (unsigned)bid * 256 + tid, ctx);
      }
    } else {
      // ---- full K=256 GEMM (waves 4-7) + red write
      if (tid == 256)            // sentinel-refill idle parity of own yt slot.
        st1_sc1(ws + OFF_SB + 16384u + (unsigned)bid * 64u + (unsigned)wr2, SENTF);
      int u = tid - 256;
      float4 h0, h1, h2, h3;
      const float* hb = ws + OFF_HD + (unsigned)rd * 65536 + (unsigned)grp * 4096 + u * 16;
      ld1q_nw(h0, hb); ld1q_nw(h1, hb + 4); ld1q_nw(h2, hb + 8); ld1q_nw(h3, hb + 12);
      vm0();
      float* row = hT + (unsigned)u * 20;
      *(float4*)(row + 0) = h0; *(float4*)(row + 4) = h1;
      *(float4*)(row + 8) = h2; *(float4*)(row + 12) = h3;
      lgk0();
      int s = u >> 6;
      float4 a0 = {0,0,0,0}, a1 = {0,0,0,0}, a2 = {0,0,0,0}, a3 = {0,0,0,0};
      const float* xp = hT + (unsigned)(s * 64) * 20 + b4 * 4;
      const float* wp = SLAB + (unsigned)(s * 64) * 64 + ml * 4;
#pragma unroll 8
      for (int kk = 0; kk < 64; ++kk) {
        float4 xv = *(const float4*)(xp + kk * 20);
        float4 wv = *(const float4*)(wp + kk * 64);
        FMA16V(a0, a1, a2, a3, xv, wv);
      }
      float* rp = red + (unsigned)(s * 64 + ml * 4 + b4) * 20;
      *(float4*)(rp + 0) = a0; *(float4*)(rp + 4) = a1;
      *(float4*)(rp + 8) = a2; *(float4*)(rp + 12) = a3;
    }
    __syncthreads();             // rejoin (red complete; attention scratch dead)

    float* hcs = SCR;            // [16][32] (attention scratch dead)
    if (tid < 256) {
      int m2 = tid & 15, bl = tid >> 4;
      int t2 = m2 * 4 + (bl >> 2), bs = bl & 3;
      float4 gate = {0,0,0,0};
#pragma unroll
      for (int k2 = 0; k2 < 4; ++k2) {
        float4 rr = *(const float4*)(red + (unsigned)(k2 * 64 + t2) * 20 + bs * 4);
        gate.x += rr.x; gate.y += rr.y; gate.z += rr.z; gate.w += rr.w;
      }
      const float* pyt = ws + OFF_SB + 16384u + (unsigned)(b0 + bl) * 64u + (unsigned)rd;
      float yt_reg = ld1s_sc1(pyt);
      while (__float_as_uint(yt_reg) == SENT_U) {
        __builtin_amdgcn_s_sleep(4);   // heavier backoff: retries are rare, keep IC calm
        yt_reg = ld1s_sc1(pyt);
      }
      float gi = gate.x + yt_reg * wiD.x + bsD.x;
      float gf = gate.y + yt_reg * wiD.y + bsD.y;
      float gg = gate.z + yt_reg * wiD.z + bsD.z;
      float go = gate.w + yt_reg * wiD.w + bsD.w;
      float cn = fast_sig(gf) * cd_reg + fast_sig(gi) * fast_tanh(gg);
      float hn = fast_sig(go) * fast_tanh(cn);
      cd_reg = cn;
      unsigned m = mt * 16 + m2;
      st1_sc1(ws + OFF_HD + (unsigned)wr2 * 65536 + (unsigned)grp * 4096 + m * 16 + bl, hn);
      hcs[bl * 32 + m2] = hn;
      hcs[bl * 32 + 16 + m2] = cn;
    }
    __syncthreads();
    {  // Sd partial STORES: 8 batches per thread, row jfixD, slot mt (no RMW)
      int half = tid >> 8;
#pragma unroll
      for (int e2 = 0; e2 < 8; ++e2) {
        int bl2 = half * 8 + e2;
        const float* hp = hcs + bl2 * 32;
        float s = 0.f;
#pragma unroll
        for (int c = 0; c < 16; ++c) s += hp[c] * wreg[c];
#pragma unroll
        for (int c = 0; c < 16; ++c) s += hp[16 + c] * wreg[16 + c];
        st1_sc1(DP + (unsigned)wr2 * 65536u + (unsigned)bl2 * 4096u
                   + (unsigned)jfixD * 16u + (unsigned)mt, s);
      }
    }
    barn += 16;
    bar_arrive(barp);
  }
  bar_wait(barp, barn);          // h_d, ctx published

  // ---------------- FINAL
  {
    float* hsf  = SCR;          // [16][516]
    float* hid2 = SCR + 8256;   // [2][16][17]
    {
      int l0 = tid * 2, l1 = tid * 2 + 1;
      int k0 = l0 >> 2, i0 = l0 & 3, k1 = l1 >> 2, i1 = l1 & 3;
      const float* hb = ws + OFF_HD + 65536u + (unsigned)grp * 4096;
      int bl0 = l0 >> 6, c0 = (l0 & 63) * 4, bl1 = l1 >> 6, c1 = (l1 & 63) * 4;
      float4 qa, qb, qc, qd;
      ld1q_nw(qa, hb + k0 * 16 + i0 * 4);
      ld1q_nw(qb, hb + k1 * 16 + i1 * 4);
      ld1q_nw(qc, ws + OFF_CTX + (unsigned)(b0 + bl0) * 256 + c0);
      ld1q_nw(qd, ws + OFF_CTX + (unsigned)(b0 + bl1) * 256 + c1);
      vm0();
      hsf[(i0 * 4 + 0) * 516 + k0] = qa.x; hsf[(i0 * 4 + 1) * 516 + k0] = qa.y;
      hsf[(i0 * 4 + 2) * 516 + k0] = qa.z; hsf[(i0 * 4 + 3) * 516 + k0] = qa.w;
      hsf[(i1 * 4 + 0) * 516 + k1] = qb.x; hsf[(i1 * 4 + 1) * 516 + k1] = qb.y;
      hsf[(i1 * 4 + 2) * 516 + k1] = qb.z; hsf[(i1 * 4 + 3) * 516 + k1] = qb.w;
      *(float4*)(hsf + bl0 * 516 + 256 + c0) = qc;
      *(float4*)(hsf + bl1 * 516 + 256 + c1) = qd;
    }
    __syncthreads();
    int bl = tid & 15, p4 = (tid >> 4) & 15, half = tid >> 8;
    int row = mt * 16 + p4;
    const float* wrow = WbW + (unsigned)row * 512 + half * 256;
    const float* hp = hsf + bl * 516 + half * 256;
    float acc = half ? 0.f : Wbb[row];
#pragma unroll 8
    for (int q = 0; q < 64; ++q)
      acc += dot4(*(const float4*)(hp + q * 4), *(const float4*)(wrow + q * 4));
    hid2[half * 272 + bl * 17 + p4] = acc;
    __syncthreads();
    if (tid < 16) {
      float s = 0.f;
#pragma unroll
      for (int p = 0; p < 16; ++p)
        s += (hid2[tid * 17 + p] + hid2[272 + tid * 17 + p]) * vbW[mt * 16 + p];
      if (mt == 0) s += vbb[0];
      atomicAdd(&out[b0 + tid], s);
    }
  }
}

extern "C" void kernel_launch(void* const* d_in, const int* in_sizes, int n_in,
                              void* d_out, int out_size, void* d_ws, size_t ws_size,
                              hipStream_t stream) {
  (void)in_sizes; (void)n_in; (void)out_size; (void)ws_size;
  const float* in    = (const float*)d_in[0];
  const float* WUe   = (const float*)d_in[1];
  const float* ve    = (const float*)d_in[2];
  const float* Wih_e = (const float*)d_in[3];
  const float* Whh_e = (const float*)d_in[4];
  const float* bih_e = (const float*)d_in[5];
  const float* bhh_e = (const float*)d_in[6];
  const float* WUd   = (const float*)d_in[7];
  const float* vd    = (const float*)d_in[8];
  const float* wbt   = (const float*)d_in[9];
  const float* Wih_d = (const float*)d_in[10];
  const float* Whh_d = (const float*)d_in[11];
  const float* bih_d = (const float*)d_in[12];
  const float* bhh_d = (const float*)d_in[13];
  const float* WbW   = (const float*)d_in[14];
  const float* Wbb   = (const float*)d_in[15];
  const float* vbW   = (const float*)d_in[16];
  const float* vbb   = (const float*)d_in[17];
  float* ws  = (float*)d_ws;
  float* out = (float*)d_out;

  (void)hipFuncSetAttribute((const void*)darnn_main,
                            hipFuncAttributeMaxDynamicSharedMemorySize, SMEM_BYTES);
  hipLaunchKernelGGL(darnn_init, dim3(1024), dim3(256), 0, stream, ws, out);
  hipLaunchKernelGGL(darnn_main, dim3(256), dim3(512), SMEM_BYTES, stream,
                     in, WUe, ve, Wih_e, Whh_e, bih_e, bhh_e,
                     WUd, vd, wbt, Wih_d, Whh_d, bih_d, bhh_d,
                     WbW, Wbb, vbW, vbb, ws, out);
}

// Round 6
// 1209.165 us; speedup vs baseline: 1.6791x; 1.6791x over previous
//
#include <hip/hip_runtime.h>
#include <math.h>

// Problem dims: B=256, T=64, N=128, M=256, P=256, YD=1
// 256 blocks x 512 threads. Group = 16 blocks = 16 batches; block role mt = m-tile.
// Wave specialization: waves 0-3 attention || waves 4-7 h-GEMM, per step.
// R6 = R5 with the partial-store LAYOUT FIXED: [parity][bl][mt][j] (j fastest).
// R5's [j][mt] layout made each wave's 64 stores hit 64 distinct lines (4B each)
// -> 2.2GB of partial-line writeback (WRITE_SIZE 599->2786MB). Now producer waves
// store contiguous 256B segments (full lines), consumers read 64-256B segments
// that are fully consumed. Replaces R4's ~520MB of atomic RMW fabric traffic and
// its 16-deep per-address serialization tail.
//   EP (encoder): XeWt slice, grp*262144 + parity*16384 + bl*1024 + mt*64 + j
//   DP (decoder): XWt slice,  grp*131072 + parity*65536 + bl*4096 + mt*256 + j
// Consumers: enc = 1 float4/lane + shfl-xor(4,8,16,32); dec = 4 float4/lane +
// shfl-xor(16,32). All other structure identical to R5 (verified correct).

// Workspace layout (float offsets)
#define OFF_XWT   0u
#define OFF_XEWT  2097152u
#define OFF_XE    6291456u
#define OFF_HE    10485760u   // [2][16][256][16] h_e transposed [buf][grp][k][bl]
#define OFF_HD    10616832u
#define OFF_SB    10747904u   // yt channel only: parity-1 rows' slots 0,1
#define OFF_SDB   10780672u   // (unused in this rev)
#define OFF_XA    10911744u   // [16][128][16]
#define OFF_CTX   10944512u
#define OFF_YT    11010048u   // (unused in this rev)
#define OFF_BAR   11010304u
#define WS_END    11010816u

#define SENT_U 0x7FC00001u

// LDS: SLAB | PER | SCR | FLG
#define SLAB_F 24576
#define PER_F  2432
#define SCR_F  12288
#define FLG_F  16
#define SMEM_F (SLAB_F + PER_F + SCR_F + FLG_F)
#define SMEM_BYTES (SMEM_F * 4)   // 157248 <= 160 KB

#define F_E 0
#define F_L 1
#define F_B 2

__device__ __forceinline__ float fast_tanh(float x) {
  float xc = fminf(15.f, fmaxf(-15.f, x));
  float e = __expf(2.f * xc);
  return 1.f - 2.f * __builtin_amdgcn_rcpf(e + 1.f);
}
__device__ __forceinline__ float fast_sig(float x) {
  float xc = fminf(30.f, fmaxf(-30.f, x));
  return __builtin_amdgcn_rcpf(1.f + __expf(-xc));
}
__device__ __forceinline__ float wave_max(float v) {
#pragma unroll
  for (int o = 32; o; o >>= 1) v = fmaxf(v, __shfl_xor(v, o));
  return v;
}
__device__ __forceinline__ float wave_sum(float v) {
#pragma unroll
  for (int o = 32; o; o >>= 1) v += __shfl_xor(v, o);
  return v;
}
__device__ __forceinline__ float dot4(float4 a, float4 b) {
  return a.x*b.x + a.y*b.y + a.z*b.z + a.w*b.w;
}

// ---- device-scope (sc1) helpers; float4 only as ASM OUTPUT ----
__device__ __forceinline__ void st1_sc1(float* p, float v) {
  asm volatile("global_store_dword %0, %1, off sc1" :: "v"(p), "v"(v) : "memory");
}
__device__ __forceinline__ void ld1q_sc1(float4& a, const float* pa) {
  asm volatile("global_load_dwordx4 %0, %1, off sc1\n\ts_waitcnt vmcnt(0)"
               : "=&v"(a) : "v"(pa) : "memory");
}
__device__ __forceinline__ void ld1q_nw(float4& a, const float* pa) {
  asm volatile("global_load_dwordx4 %0, %1, off sc1"
               : "=&v"(a) : "v"(pa) : "memory");
}
__device__ __forceinline__ void vm0() {
  asm volatile("s_waitcnt vmcnt(0)" ::: "memory");
}
__device__ __forceinline__ void lgk0() {
  asm volatile("s_waitcnt lgkmcnt(0)" ::: "memory");
}
__device__ __forceinline__ float ld1s_sc1(const float* p) {
  float v;
  asm volatile("global_load_dword %0, %1, off sc1\n\ts_waitcnt vmcnt(0)"
               : "=&v"(v) : "v"(p) : "memory");
  return v;
}
__device__ __forceinline__ void ld8s_sc1(
    float& a0,float& a1,float& a2,float& a3,float& a4,float& a5,float& a6,float& a7,
    const float* p0,const float* p1,const float* p2,const float* p3,
    const float* p4,const float* p5,const float* p6,const float* p7) {
  asm volatile(
      "global_load_dword %0, %8, off sc1\n\t"
      "global_load_dword %1, %9, off sc1\n\t"
      "global_load_dword %2, %10, off sc1\n\t"
      "global_load_dword %3, %11, off sc1\n\t"
      "global_load_dword %4, %12, off sc1\n\t"
      "global_load_dword %5, %13, off sc1\n\t"
      "global_load_dword %6, %14, off sc1\n\t"
      "global_load_dword %7, %15, off sc1\n\t"
      "s_waitcnt vmcnt(0)"
      : "=&v"(a0),"=&v"(a1),"=&v"(a2),"=&v"(a3),
        "=&v"(a4),"=&v"(a5),"=&v"(a6),"=&v"(a7)
      : "v"(p0),"v"(p1),"v"(p2),"v"(p3),"v"(p4),"v"(p5),"v"(p6),"v"(p7)
      : "memory");
}

// LDS flag sync (monotonic counters; subset-of-waves sync without s_barrier)
__device__ __forceinline__ void lds_inc(unsigned* f) {
  __hip_atomic_fetch_add(f, 1u, __ATOMIC_RELAXED, __HIP_MEMORY_SCOPE_WORKGROUP);
}
__device__ __forceinline__ void lds_poll(unsigned* f, unsigned tgt) {
  unsigned cur;
  do { cur = __hip_atomic_load(f, __ATOMIC_RELAXED, __HIP_MEMORY_SCOPE_WORKGROUP); } while (cur < tgt);
  asm volatile("" ::: "memory");
}

#define FMA16V(a0,a1,a2,a3,xv,wv) \
  a0.x += xv.x*wv.x; a0.y += xv.x*wv.y; a0.z += xv.x*wv.z; a0.w += xv.x*wv.w; \
  a1.x += xv.y*wv.x; a1.y += xv.y*wv.y; a1.z += xv.y*wv.z; a1.w += xv.y*wv.w; \
  a2.x += xv.z*wv.x; a2.y += xv.z*wv.y; a2.z += xv.z*wv.z; a2.w += xv.z*wv.w; \
  a3.x += xv.w*wv.x; a3.y += xv.w*wv.y; a3.z += xv.w*wv.z; a3.w += xv.w*wv.w;

// Split fence-free group barrier (monotonic counter, relaxed agent atomics)
__device__ __forceinline__ void bar_arrive(unsigned* bar) {
  asm volatile("s_waitcnt vmcnt(0)" ::: "memory");
  __syncthreads();
  if (threadIdx.x == 0)
    __hip_atomic_fetch_add(bar, 1u, __ATOMIC_RELAXED, __HIP_MEMORY_SCOPE_AGENT);
}
__device__ __forceinline__ void bar_wait(unsigned* bar, unsigned target) {
  if (threadIdx.x == 0) {
    unsigned cur;
    do {
      __builtin_amdgcn_s_sleep(1);   // backoff: avoid IC poll livelock
      cur = __hip_atomic_load(bar, __ATOMIC_RELAXED, __HIP_MEMORY_SCOPE_AGENT);
    } while (cur < target);
  }
  __syncthreads();
}

__global__ void darnn_init(float* __restrict__ ws, float* __restrict__ out) {
  unsigned i = blockIdx.x * 256u + threadIdx.x;
  const unsigned span = WS_END - OFF_HE;
  for (unsigned idx = i; idx < span; idx += gridDim.x * 256u) ws[OFF_HE + idx] = 0.f;
  // zero EP[0] (encoder S-partials, parity 0) in each group's XeWt slice
  for (unsigned idx = i; idx < 262144u; idx += gridDim.x * 256u) {
    unsigned g = idx >> 14, off = idx & 16383u;
    ws[OFF_XEWT + g * 262144u + off] = 0.f;
  }
  if (i < 256u) out[i] = 0.f;
}

__global__ __launch_bounds__(512, 2) void darnn_main(
    const float* __restrict__ in,   const float* __restrict__ WUe,   const float* __restrict__ ve,
    const float* __restrict__ Wih_e,const float* __restrict__ Whh_e,
    const float* __restrict__ bih_e,const float* __restrict__ bhh_e,
    const float* __restrict__ WUd,  const float* __restrict__ vd,
    const float* __restrict__ wbt,  const float* __restrict__ Wih_d,
    const float* __restrict__ Whh_d,const float* __restrict__ bih_d, const float* __restrict__ bhh_d,
    const float* __restrict__ WbW,  const float* __restrict__ Wbb,
    const float* __restrict__ vbW,  const float* __restrict__ vbb,
    float* __restrict__ ws, float* __restrict__ out)
{
  extern __shared__ __align__(16) float sm[];
  float* SLAB = sm;
  float* PER  = sm + SLAB_F;
  float* SCR  = sm + SLAB_F + PER_F;
  unsigned* FLG = (unsigned*)(sm + SLAB_F + PER_F + SCR_F);
  const int tid = threadIdx.x;
  const int bid = blockIdx.x;
  const int grp = bid >> 4;
  const int mt  = bid & 15;
  const int b0  = grp << 4;
  const float SENTF = __uint_as_float(SENT_U);

  float* XWt  = ws + OFF_XWT;
  float* XeWt = ws + OFF_XEWT;
  float* Xe   = ws + OFF_XE;
  // partial-slot bases ([parity][bl][mt][j], j fastest)
  float* EP = ws + OFF_XEWT + (unsigned)grp * 262144u;  // [2][16][16][64]
  float* DP = ws + OFF_XWT  + (unsigned)grp * 131072u;  // [2][16][16][256]
  unsigned* barp = (unsigned*)(ws + OFF_BAR) + grp * 32;
  unsigned barn = 0;

  if (tid < FLG_F) FLG[tid] = 0u;

  // PER (encoder): wue_s [64][36]; ve_s @2304; bsum_e @2368
  float* wue_s  = PER;
  float* ve_s   = PER + 2304;
  float* bsum_e = PER + 2368;

  // rotated S-row for this thread's partial sweep (de-phases store bursts)
  const int jfixE = ((tid & 63) + mt * 4) & 63;

  // ---- one-time encoder staging ----
  {
    int r = tid & 63, kq = tid >> 6;
    int grow = (r & 3) * 256 + mt * 16 + (r >> 2);
#pragma unroll 4
    for (int q = 0; q < 12; ++q) {
      int k = kq * 48 + q * 4;
      float4 wv = (k < 128) ? *(const float4*)(Wih_e + grow * 128 + k)
                            : *(const float4*)(Whh_e + grow * 256 + (k - 128));
      SLAB[(k + 0) * 64 + r] = wv.x; SLAB[(k + 1) * 64 + r] = wv.y;
      SLAB[(k + 2) * 64 + r] = wv.z; SLAB[(k + 3) * 64 + r] = wv.w;
    }
    {
      int lin = tid * 4;
      int j = lin >> 5, c0 = lin & 31;
      int col = (c0 < 16) ? (mt * 16 + c0) : (256 + mt * 16 + (c0 - 16));
      float4 wv = *(const float4*)(WUe + j * 576 + col);
      *(float4*)(wue_s + j * 36 + c0) = wv;
    }
    if (tid < 64) {
      ve_s[tid] = ve[tid];
      int g = tid >> 4, m2 = tid & 15, m = mt * 16 + m2;
      bsum_e[tid] = bih_e[g * 256 + m] + bhh_e[g * 256 + m];
    }
  }

  // ---------------- P1: XWt[bid][j][n] = sum_k X[bid][k][n] * WU_e[j][512+k]
  {
    float* Xs = SCR;  // [128][68]
    const float* Xb = in + bid * 8256;
    __syncthreads();
    for (int it = 0; it < 16; ++it) {
      int lin = tid + it * 512;
      int k = lin >> 7, n = lin & 127;
      Xs[n * 68 + k] = Xb[k * 129 + n];
    }
    __syncthreads();
    int j = tid & 63, nh = tid >> 6;
    float acc[16];
#pragma unroll
    for (int i = 0; i < 16; ++i) acc[i] = 0.f;
    const float* wrow = WUe + j * 576 + 512;
    for (int kc = 0; kc < 4; ++kc) {
      float4 w0 = *(const float4*)(wrow + kc * 16 + 0);
      float4 w1 = *(const float4*)(wrow + kc * 16 + 4);
      float4 w2 = *(const float4*)(wrow + kc * 16 + 8);
      float4 w3 = *(const float4*)(wrow + kc * 16 + 12);
#pragma unroll
      for (int ni = 0; ni < 16; ++ni) {
        const float* xp = Xs + (nh * 16 + ni) * 68 + kc * 16;
        acc[ni] += dot4(*(const float4*)(xp + 0),  w0) + dot4(*(const float4*)(xp + 4),  w1)
                 + dot4(*(const float4*)(xp + 8),  w2) + dot4(*(const float4*)(xp + 12), w3);
      }
    }
    float* dst = XWt + bid * 8192 + j * 128 + nh * 16;
#pragma unroll
    for (int ni = 0; ni < 16; ++ni) dst[ni] = acc[ni];
    __syncthreads();
  }

  // hoist regs (constant over t); whc holds weights for ROTATED row jfixE
  float4 whc[8];
#pragma unroll
  for (int q = 0; q < 8; ++q) whc[q] = *(const float4*)(wue_s + jfixE * 36 + q * 4);
  float4 bsE = {0,0,0,0};
  {
    int m2 = tid & 15;
    bsE.x = bsum_e[m2]; bsE.y = bsum_e[16 + m2];
    bsE.z = bsum_e[32 + m2]; bsE.w = bsum_e[48 + m2];
  }
  // xwreg: wave w (0-3), lane l: n in {l, l+64}, j in w*16..+15
  float xwreg[32];
  if (tid < 256) {
    int w = tid >> 6, l = tid & 63;
    const float* xwp = XWt + bid * 8192;
#pragma unroll
    for (int jj = 0; jj < 16; ++jj) {
      xwreg[jj]      = xwp[(w * 16 + jj) * 128 + l];
      xwreg[16 + jj] = xwp[(w * 16 + jj) * 128 + 64 + l];
    }
  }
  float c_reg = 0.f;

  // ================ ENCODER: 64 steps ================
  for (int t = 0; t < 64; ++t) {
    const int rd = t & 1, wr2 = (t + 1) & 1;
    float* xah = SCR + 1024;     // [384][20]
    const int ks = tid >> 6, ml = (tid >> 2) & 15, b4 = tid & 3;
    float4 a0 = {0,0,0,0}, a1 = {0,0,0,0}, a2 = {0,0,0,0}, a3 = {0,0,0,0};

    bar_wait(barp, barn);        // EP(rd), h(rd) visible

    if (tid < 256) {
      // ---- attention (waves 0-3), arrives event B at the end (wave 0)
      int w = tid >> 6, l = tid & 63;
      float* Sj = SCR;           // [64]
      float* Ep = SCR + 64;      // [4][128]
      {  // gather S partials ([mt][j]): 1 float4/lane, shfl-reduce over mt (l>>2)
        float4 s;
        ld1q_sc1(s, EP + (unsigned)rd * 16384u + (unsigned)mt * 1024u
                       + (unsigned)((l >> 2) * 64 + w * 16 + (l & 3) * 4));
#pragma unroll
        for (int off = 4; off <= 32; off <<= 1) {
          s.x += __shfl_xor(s.x, off);
          s.y += __shfl_xor(s.y, off);
          s.z += __shfl_xor(s.z, off);
          s.w += __shfl_xor(s.w, off);
        }
        if (l < 4) *(float4*)(Sj + w * 16 + l * 4) = s;
        lgk0();
      }
      float e0 = 0.f, e1 = 0.f;
#pragma unroll
      for (int jj = 0; jj < 16; ++jj) {
        float s = Sj[w * 16 + jj];
        float vv = ve_s[w * 16 + jj];
        e0 += vv * fast_tanh(xwreg[jj] + s);
        e1 += vv * fast_tanh(xwreg[16 + jj] + s);
      }
      Ep[w * 128 + l] = e0;
      Ep[w * 128 + 64 + l] = e1;
      lgk0();
      if (l == 0) lds_inc(FLG + F_E);
      if (w == 0) {
        lds_poll(FLG + F_E, 4u * (t + 1));
        float En0 = Ep[l] + Ep[128 + l] + Ep[256 + l] + Ep[384 + l];
        float En1 = Ep[64 + l] + Ep[192 + l] + Ep[320 + l] + Ep[448 + l];
        float mx = wave_max(fmaxf(En0, En1));
        float ex0 = __expf(En0 - mx), ex1 = __expf(En1 - mx);
        float tot = wave_sum(ex0 + ex1);
        float rt = __builtin_amdgcn_rcpf(tot);
        float x0 = in[bid * 8256 + t * 129 + l];
        float x1 = in[bid * 8256 + t * 129 + 64 + l];
        float* XAg = ws + OFF_XA + (unsigned)grp * 2048;
        st1_sc1(XAg + l * 16 + mt, x0 * ex0 * rt);
        st1_sc1(XAg + (64 + l) * 16 + mt, x1 * ex1 * rt);
        vm0();
        if (tid == 0)
          __hip_atomic_fetch_add(barp, 1u, __ATOMIC_RELAXED, __HIP_MEMORY_SCOPE_AGENT);
      }
    } else {
      // ---- h-part GEMM (waves 4-7): k in [128,384)
      int u = tid - 256;
      float4 h0, h1, h2, h3;
      const float* hb = ws + OFF_HE + (unsigned)rd * 65536 + (unsigned)grp * 4096 + u * 16;
      ld1q_nw(h0, hb); ld1q_nw(h1, hb + 4); ld1q_nw(h2, hb + 8); ld1q_nw(h3, hb + 12);
      vm0();
      float* row = xah + (unsigned)(128 + u) * 20;
      *(float4*)(row + 0) = h0; *(float4*)(row + 4) = h1;
      *(float4*)(row + 8) = h2; *(float4*)(row + 12) = h3;
      lgk0();
      int s = u >> 6;
      const float* xp = xah + (unsigned)(128 + s * 64) * 20 + b4 * 4;
      const float* wp = SLAB + (unsigned)(128 + s * 64) * 64 + ml * 4;
#pragma unroll 8
      for (int kk = 0; kk < 64; ++kk) {
        float4 xv = *(const float4*)(xp + kk * 20);
        float4 wv = *(const float4*)(wp + kk * 64);
        FMA16V(a0, a1, a2, a3, xv, wv);
      }
    }
    barn += 16;
    bar_wait(barp, barn);        // all XAs visible (internal sync rejoins waves)

    // plant decoder yt-channel sentinels once (parity-1 slots 0,1); drains at arrive
    if (t == 63 && tid == 0) {
      float* sp = ws + OFF_SB + 16384u + (unsigned)bid * 64u;
      st1_sc1(sp + 0, SENTF); st1_sc1(sp + 1, SENTF);
    }
    {  // per-wave XA staging: wave ks stages exactly rows ks*16..+15 it consumes
      int l = tid & 63;
      int k = (ks << 4) + (l >> 2), i4 = (l & 3) * 4;
      float4 q;
      ld1q_sc1(q, ws + OFF_XA + (unsigned)grp * 2048 + k * 16 + i4);
      *(float4*)(xah + k * 20 + i4) = q;
      lgk0();                    // wave-local: no block sync needed
    }
    {  // x-part: 8 strips x 16 k
      const float* xp = xah + (unsigned)(ks * 16) * 20 + b4 * 4;
      const float* wp = SLAB + (unsigned)(ks * 16) * 64 + ml * 4;
#pragma unroll 8
      for (int kk = 0; kk < 16; ++kk) {
        float4 xv = *(const float4*)(xp + kk * 20);
        float4 wv = *(const float4*)(wp + kk * 64);
        FMA16V(a0, a1, a2, a3, xv, wv);
      }
    }
    __syncthreads();             // xah dead -> red
    float* red = SCR;            // [512][20]
    {
      float* rp = red + (unsigned)(ks * 64 + ml * 4 + b4) * 20;
      *(float4*)(rp + 0) = a0; *(float4*)(rp + 4) = a1;
      *(float4*)(rp + 8) = a2; *(float4*)(rp + 12) = a3;
    }
    __syncthreads();
    float* hcs = SCR + 10240;    // [16][32]
    if (tid < 256) {
      int m2 = tid & 15, bl = tid >> 4;
      int t2 = m2 * 4 + (bl >> 2), bs = bl & 3;
      float4 gate = {0,0,0,0};
#pragma unroll
      for (int k2 = 0; k2 < 8; ++k2) {
        float4 rr = *(const float4*)(red + (unsigned)(k2 * 64 + t2) * 20 + bs * 4);
        gate.x += rr.x; gate.y += rr.y; gate.z += rr.z; gate.w += rr.w;
      }
      float gi = gate.x + bsE.x, gf = gate.y + bsE.y;
      float gg = gate.z + bsE.z, go = gate.w + bsE.w;
      float cn = fast_sig(gf) * c_reg + fast_sig(gi) * fast_tanh(gg);
      float hn = fast_sig(go) * fast_tanh(cn);
      c_reg = cn;
      unsigned m = mt * 16 + m2;
      st1_sc1(ws + OFF_HE + (unsigned)wr2 * 65536 + (unsigned)grp * 4096 + m * 16 + bl, hn);
      st1_sc1(Xe + ((unsigned)(b0 + bl) * 64 + t) * 256 + m, hn);
      hcs[bl * 32 + m2] = hn;
      hcs[bl * 32 + 16 + m2] = cn;
    }
    __syncthreads();
    {  // S partial STORES: [bl][mt][j] layout -> wave stores 256B contiguous
      int wq = tid >> 6;
#pragma unroll
      for (int e2 = 0; e2 < 2; ++e2) {
        int bl2 = wq * 2 + e2;
        const float* hp = hcs + bl2 * 32;
        float s = 0.f;
#pragma unroll
        for (int q = 0; q < 4; ++q) {
          s += dot4(*(const float4*)(hp + q * 4), whc[q]);
          s += dot4(*(const float4*)(hp + 16 + q * 4), whc[4 + q]);
        }
        st1_sc1(EP + (unsigned)wr2 * 16384u + (unsigned)bl2 * 1024u
                   + (unsigned)mt * 64u + (unsigned)jfixE, s);
      }
    }
    barn += 16;
    bar_arrive(barp);
  }
  bar_wait(barp, barn);          // all Xe published

  // ---- fill Xe row into regs: tid<256, m = tid, all 64 t
  float xe[64];
  if (tid < 256) {
    const float* xb = Xe + (unsigned)bid * 16384 + tid;
#pragma unroll
    for (int g8 = 0; g8 < 8; ++g8) {
      ld8s_sc1(xe[g8*8+0], xe[g8*8+1], xe[g8*8+2], xe[g8*8+3],
               xe[g8*8+4], xe[g8*8+5], xe[g8*8+6], xe[g8*8+7],
               xb + (g8*8+0)*256, xb + (g8*8+1)*256, xb + (g8*8+2)*256,
               xb + (g8*8+3)*256, xb + (g8*8+4)*256, xb + (g8*8+5)*256,
               xb + (g8*8+6)*256, xb + (g8*8+7)*256);
    }
  }

  // ---- decoder one-time staging ----
  float* vd_s   = PER;
  float* wbt_s  = PER + 256;
  float* bsum_d = PER + 520;
  float* wihd_s = PER + 584;
  float* q_s    = PER + 704;      // [64] q[t'] = sum_m wbt[1+m]*Xe[b][t'][m]
  float* qpart  = PER + 768;      // [4][64] scratch
  float* wudT   = SLAB + 16384;   // [32][256]
  const int jfixD = ((tid & 255) + mt * 16) & 255;
  __syncthreads();
  {
    int r = tid & 63, kq = tid >> 6;
    int grow = (r & 3) * 256 + mt * 16 + (r >> 2);
#pragma unroll 4
    for (int q = 0; q < 8; ++q) {
      int k = kq * 32 + q * 4;
      float4 wv = *(const float4*)(Whh_d + grow * 256 + k);
      SLAB[(k + 0) * 64 + r] = wv.x; SLAB[(k + 1) * 64 + r] = wv.y;
      SLAB[(k + 2) * 64 + r] = wv.z; SLAB[(k + 3) * 64 + r] = wv.w;
    }
    {
      int j = tid & 255, half = tid >> 8;
#pragma unroll
      for (int i = 0; i < 16; ++i) {
        int c = half * 16 + i;
        int col = (c < 16) ? (mt * 16 + c) : (256 + mt * 16 + (c - 16));
        wudT[c * 256 + j] = WUd[(unsigned)j * 768 + col];
      }
    }
    if (tid < 256) vd_s[tid] = vd[tid];
    if (tid < 257) wbt_s[tid] = wbt[tid];
    if (tid < 64) {
      int g = tid >> 4, m2 = tid & 15, m = mt * 16 + m2;
      bsum_d[tid] = bih_d[g * 256 + m] + bhh_d[g * 256 + m];
      wihd_s[tid] = Wih_d[g * 256 + m];
    }
  }
  __syncthreads();

  // ---- q precompute: q[t'] = sum_m wbt[1+m] * Xe[b][t'][m]  (one-time)
  if (tid < 256) {
    int w = tid >> 6, l = tid & 63;
    float wm = wbt_s[1 + tid];
#pragma unroll
    for (int t4 = 0; t4 < 64; ++t4) {
      float v = wave_sum(wm * xe[t4]);
      if (l == 0) qpart[w * 64 + t4] = v;
    }
  }
  __syncthreads();
  if (tid < 64) q_s[tid] = qpart[tid] + qpart[64 + tid] + qpart[128 + tid] + qpart[192 + tid];
  __syncthreads();

  // ---------------- P2: XeWt[bid][j][t'] = sum_k Xe[bid][t'][k] * WU_d[j][512+k]
  // (overwrites EP region — EP is dead after the encoder)
  {
    float* XeT = SCR;          // [64][64]
    float* Wdc = SCR + 4096;   // [64][128]
    int tt2 = tid & 15, jq = tid >> 4;
    for (int jc = 0; jc < 2; ++jc) {
      float4 c0 = {0,0,0,0}, c1 = {0,0,0,0}, c2 = {0,0,0,0}, c3 = {0,0,0,0};
      for (int kc = 0; kc < 4; ++kc) {
        __syncthreads();
        if (tid < 256 && (tid >> 6) == kc) {
          int kk = tid & 63;
#pragma unroll
          for (int t4 = 0; t4 < 16; ++t4) {
            float4 v = { xe[t4*4+0], xe[t4*4+1], xe[t4*4+2], xe[t4*4+3] };
            *(float4*)(XeT + kk * 64 + t4 * 4) = v;
          }
        }
        {
          int jj = tid >> 2, k16 = (tid & 3) * 16;
          const float* src = WUd + (unsigned)(jc * 128 + jj) * 768 + 512 + kc * 64 + k16;
#pragma unroll
          for (int s4 = 0; s4 < 4; ++s4) {
            float4 wv = *(const float4*)(src + s4 * 4);
            Wdc[(k16 + s4*4 + 0) * 128 + jj] = wv.x;
            Wdc[(k16 + s4*4 + 1) * 128 + jj] = wv.y;
            Wdc[(k16 + s4*4 + 2) * 128 + jj] = wv.z;
            Wdc[(k16 + s4*4 + 3) * 128 + jj] = wv.w;
          }
        }
        __syncthreads();
#pragma unroll 8
        for (int kk = 0; kk < 64; ++kk) {
          float4 xv = *(const float4*)(XeT + kk * 64 + tt2 * 4);
          float4 wv = *(const float4*)(Wdc + kk * 128 + jq * 4);
          FMA16V(c0, c1, c2, c3, wv, xv);
        }
      }
      int jb = jc * 128 + jq * 4;
      *(float4*)(XeWt + ((unsigned)bid * 256 + jb + 0) * 64 + tt2 * 4) = c0;
      *(float4*)(XeWt + ((unsigned)bid * 256 + jb + 1) * 64 + tt2 * 4) = c1;
      *(float4*)(XeWt + ((unsigned)bid * 256 + jb + 2) * 64 + tt2 * 4) = c2;
      *(float4*)(XeWt + ((unsigned)bid * 256 + jb + 3) * 64 + tt2 * 4) = c3;
    }
    __syncthreads();
  }

  // hoist decoder regs; wreg for ROTATED row jfixD
  float wreg[32];
#pragma unroll
  for (int c = 0; c < 32; ++c) wreg[c] = wudT[c * 256 + jfixD];
  float4 bsD = {0,0,0,0}, wiD = {0,0,0,0};
  {
    int m2 = tid & 15;
    bsD.x = bsum_d[m2]; bsD.y = bsum_d[16 + m2]; bsD.z = bsum_d[32 + m2]; bsD.w = bsum_d[48 + m2];
    wiD.x = wihd_s[m2]; wiD.y = wihd_s[16 + m2]; wiD.z = wihd_s[32 + m2]; wiD.w = wihd_s[48 + m2];
  }
  // xewreg: wave w (0-3), lane l = t': j in w*64..+63
  float xewreg[64];
  if (tid < 256) {
    int w = tid >> 6, l = tid & 63;
    const float* xew = XeWt + (unsigned)bid * 16384 + l;
#pragma unroll
    for (int jj = 0; jj < 64; ++jj) xewreg[jj] = xew[(w * 64 + jj) << 6];
  }
  // wave0 per-lane hoists: q[l] and y-input y_t for t=l (shfl'd per step)
  float q_reg = 0.f, yv = 0.f;
  if (tid < 64) {
    q_reg = q_s[tid];
    if (tid < 63) yv = in[bid * 8256 + tid * 129 + 128];
  }
  const float wbt0 = wbt_s[0];
  float cd_reg = 0.f;

  // ---- zero DP[0] (decoder S-partials, parity 0), own 4096-float slice,
  //      then ONE extra group barrier so step-0 consumers see the zeros.
  {
    float* dp0 = DP + (unsigned)mt * 4096u;
#pragma unroll
    for (int i8 = 0; i8 < 8; ++i8) st1_sc1(dp0 + (unsigned)(i8 * 512 + tid), 0.f);
    barn += 16;
    bar_arrive(barp);
  }

  // ================ DECODER: 63 steps ================
  // yt channel: slots 0/1 of SB parity-1 rows (sentineled at encoder t=63).
  // Barrier accounting: ONE bar_arrive (+16) per step; barn advances by 16.
  for (int t = 0; t < 63; ++t) {
    const int rd = t & 1, wr2 = (t + 1) & 1;
    const int ml = (tid >> 2) & 15, b4 = tid & 3;
    float* hT  = SCR + 2048;     // [256][20]
    float* red = SCR + 7168;     // [256][20]

    bar_wait(barp, barn);        // DP(rd), h(rd), yt-refill(rd from t-1) visible

    if (tid < 256) {
      // ---- attention (waves 0-3); wave0 publishes yt right after softmax (q-trick)
      int w = tid >> 6, l = tid & 63;
      float* Sdj  = SCR;         // [256]
      float* lp   = SCR + 256;   // [4][64]
      float* beta = SCR + 512;   // [64] (t==62 only)
      {  // gather Sd partials ([mt][j]): 4x float4/lane + shfl-reduce over mt (l>>4)
        int jq = (l & 15) * 4, mq = l >> 4;
        const float* dpb = DP + (unsigned)rd * 65536u + (unsigned)mt * 4096u
                              + (unsigned)(w * 64 + jq);
        float4 p0, p1, p2, p3;
        ld1q_nw(p0, dpb + (unsigned)((mq +  0) * 256));
        ld1q_nw(p1, dpb + (unsigned)((mq +  4) * 256));
        ld1q_nw(p2, dpb + (unsigned)((mq +  8) * 256));
        ld1q_nw(p3, dpb + (unsigned)((mq + 12) * 256));
        vm0();
        float4 s;
        s.x = (p0.x + p1.x) + (p2.x + p3.x);
        s.y = (p0.y + p1.y) + (p2.y + p3.y);
        s.z = (p0.z + p1.z) + (p2.z + p3.z);
        s.w = (p0.w + p1.w) + (p2.w + p3.w);
#pragma unroll
        for (int off = 16; off <= 32; off <<= 1) {
          s.x += __shfl_xor(s.x, off);
          s.y += __shfl_xor(s.y, off);
          s.z += __shfl_xor(s.z, off);
          s.w += __shfl_xor(s.w, off);
        }
        if (mq == 0) *(float4*)(Sdj + w * 64 + jq) = s;
        lgk0();
      }
      float lpar = 0.f;
#pragma unroll 8
      for (int jj = 0; jj < 64; ++jj)
        lpar += vd_s[w * 64 + jj] * fast_tanh(xewreg[jj] + Sdj[w * 64 + jj]);
      lp[w * 64 + l] = lpar;
      lgk0();
      if (l == 0) lds_inc(FLG + F_L);
      if (w == 0) {
        lds_poll(FLG + F_L, 4u * (t + 1));
        float lv = lp[l] + lp[64 + l] + lp[128 + l] + lp[192 + l];
        float mx = wave_max(lv);
        float ex = __expf(lv - mx);
        float sw = wave_sum(ex);
        float rt = __builtin_amdgcn_rcpf(sw);
        float ytn = wave_sum(ex * q_reg);
        if (l == 0) {
          float yt = wbt0 * __shfl(yv, t) + ytn * rt;
          st1_sc1(ws + OFF_SB + 16384u + (unsigned)bid * 64u + (unsigned)rd, yt);
        }
        // fire-and-forget: consumers sentinel-poll; drain happens at bar_arrive
        if (t == 62) {
          beta[l] = ex * rt;
          lgk0();
          if (l == 0) lds_inc(FLG + F_B);
        }
      }
      if (t == 62) {             // ctx only needed by FINAL
        lds_poll(FLG + F_B, 1u);
        lgk0();
        float ctx = 0.f;
#pragma unroll
        for (int tt = 0; tt < 64; ++tt) ctx += beta[tt] * xe[tt];
        st1_sc1(ws + OFF_CTX + (unsigned)bid * 256 + tid, ctx);
      }
    } else {
      // ---- full K=256 GEMM (waves 4-7) + red write
      if (tid == 256)            // sentinel-refill idle parity of own yt slot.
        st1_sc1(ws + OFF_SB + 16384u + (unsigned)bid * 64u + (unsigned)wr2, SENTF);
      int u = tid - 256;
      float4 h0, h1, h2, h3;
      const float* hb = ws + OFF_HD + (unsigned)rd * 65536 + (unsigned)grp * 4096 + u * 16;
      ld1q_nw(h0, hb); ld1q_nw(h1, hb + 4); ld1q_nw(h2, hb + 8); ld1q_nw(h3, hb + 12);
      vm0();
      float* row = hT + (unsigned)u * 20;
      *(float4*)(row + 0) = h0; *(float4*)(row + 4) = h1;
      *(float4*)(row + 8) = h2; *(float4*)(row + 12) = h3;
      lgk0();
      int s = u >> 6;
      float4 a0 = {0,0,0,0}, a1 = {0,0,0,0}, a2 = {0,0,0,0}, a3 = {0,0,0,0};
      const float* xp = hT + (unsigned)(s * 64) * 20 + b4 * 4;
      const float* wp = SLAB + (unsigned)(s * 64) * 64 + ml * 4;
#pragma unroll 8
      for (int kk = 0; kk < 64; ++kk) {
        float4 xv = *(const float4*)(xp + kk * 20);
        float4 wv = *(const float4*)(wp + kk * 64);
        FMA16V(a0, a1, a2, a3, xv, wv);
      }
      float* rp = red + (unsigned)(s * 64 + ml * 4 + b4) * 20;
      *(float4*)(rp + 0) = a0; *(float4*)(rp + 4) = a1;
      *(float4*)(rp + 8) = a2; *(float4*)(rp + 12) = a3;
    }
    __syncthreads();             // rejoin (red complete; attention scratch dead)

    float* hcs = SCR;            // [16][32] (attention scratch dead)
    if (tid < 256) {
      int m2 = tid & 15, bl = tid >> 4;
      int t2 = m2 * 4 + (bl >> 2), bs = bl & 3;
      float4 gate = {0,0,0,0};
#pragma unroll
      for (int k2 = 0; k2 < 4; ++k2) {
        float4 rr = *(const float4*)(red + (unsigned)(k2 * 64 + t2) * 20 + bs * 4);
        gate.x += rr.x; gate.y += rr.y; gate.z += rr.z; gate.w += rr.w;
      }
      const float* pyt = ws + OFF_SB + 16384u + (unsigned)(b0 + bl) * 64u + (unsigned)rd;
      float yt_reg = ld1s_sc1(pyt);
      while (__float_as_uint(yt_reg) == SENT_U) {
        __builtin_amdgcn_s_sleep(4);   // heavier backoff: retries are rare, keep IC calm
        yt_reg = ld1s_sc1(pyt);
      }
      float gi = gate.x + yt_reg * wiD.x + bsD.x;
      float gf = gate.y + yt_reg * wiD.y + bsD.y;
      float gg = gate.z + yt_reg * wiD.z + bsD.z;
      float go = gate.w + yt_reg * wiD.w + bsD.w;
      float cn = fast_sig(gf) * cd_reg + fast_sig(gi) * fast_tanh(gg);
      float hn = fast_sig(go) * fast_tanh(cn);
      cd_reg = cn;
      unsigned m = mt * 16 + m2;
      st1_sc1(ws + OFF_HD + (unsigned)wr2 * 65536 + (unsigned)grp * 4096 + m * 16 + bl, hn);
      hcs[bl * 32 + m2] = hn;
      hcs[bl * 32 + 16 + m2] = cn;
    }
    __syncthreads();
    {  // Sd partial STORES: [bl][mt][j] layout -> wave stores 256B contiguous
      int half = tid >> 8;
#pragma unroll
      for (int e2 = 0; e2 < 8; ++e2) {
        int bl2 = half * 8 + e2;
        const float* hp = hcs + bl2 * 32;
        float s = 0.f;
#pragma unroll
        for (int c = 0; c < 16; ++c) s += hp[c] * wreg[c];
#pragma unroll
        for (int c = 0; c < 16; ++c) s += hp[16 + c] * wreg[16 + c];
        st1_sc1(DP + (unsigned)wr2 * 65536u + (unsigned)bl2 * 4096u
                   + (unsigned)mt * 256u + (unsigned)jfixD, s);
      }
    }
    barn += 16;
    bar_arrive(barp);
  }
  bar_wait(barp, barn);          // h_d, ctx published

  // ---------------- FINAL
  {
    float* hsf  = SCR;          // [16][516]
    float* hid2 = SCR + 8256;   // [2][16][17]
    {
      int l0 = tid * 2, l1 = tid * 2 + 1;
      int k0 = l0 >> 2, i0 = l0 & 3, k1 = l1 >> 2, i1 = l1 & 3;
      const float* hb = ws + OFF_HD + 65536u + (unsigned)grp * 4096;
      int bl0 = l0 >> 6, c0 = (l0 & 63) * 4, bl1 = l1 >> 6, c1 = (l1 & 63) * 4;
      float4 qa, qb, qc, qd;
      ld1q_nw(qa, hb + k0 * 16 + i0 * 4);
      ld1q_nw(qb, hb + k1 * 16 + i1 * 4);
      ld1q_nw(qc, ws + OFF_CTX + (unsigned)(b0 + bl0) * 256 + c0);
      ld1q_nw(qd, ws + OFF_CTX + (unsigned)(b0 + bl1) * 256 + c1);
      vm0();
      hsf[(i0 * 4 + 0) * 516 + k0] = qa.x; hsf[(i0 * 4 + 1) * 516 + k0] = qa.y;
      hsf[(i0 * 4 + 2) * 516 + k0] = qa.z; hsf[(i0 * 4 + 3) * 516 + k0] = qa.w;
      hsf[(i1 * 4 + 0) * 516 + k1] = qb.x; hsf[(i1 * 4 + 1) * 516 + k1] = qb.y;
      hsf[(i1 * 4 + 2) * 516 + k1] = qb.z; hsf[(i1 * 4 + 3) * 516 + k1] = qb.w;
      *(float4*)(hsf + bl0 * 516 + 256 + c0) = qc;
      *(float4*)(hsf + bl1 * 516 + 256 + c1) = qd;
    }
    __syncthreads();
    int bl = tid & 15, p4 = (tid >> 4) & 15, half = tid >> 8;
    int row = mt * 16 + p4;
    const float* wrow = WbW + (unsigned)row * 512 + half * 256;
    const float* hp = hsf + bl * 516 + half * 256;
    float acc = half ? 0.f : Wbb[row];
#pragma unroll 8
    for (int q = 0; q < 64; ++q)
      acc += dot4(*(const float4*)(hp + q * 4), *(const float4*)(wrow + q * 4));
    hid2[half * 272 + bl * 17 + p4] = acc;
    __syncthreads();
    if (tid < 16) {
      float s = 0.f;
#pragma unroll
      for (int p = 0; p < 16; ++p)
        s += (hid2[tid * 17 + p] + hid2[272 + tid * 17 + p]) * vbW[mt * 16 + p];
      if (mt == 0) s += vbb[0];
      atomicAdd(&out[b0 + tid], s);
    }
  }
}

extern "C" void kernel_launch(void* const* d_in, const int* in_sizes, int n_in,
                              void* d_out, int out_size, void* d_ws, size_t ws_size,
                              hipStream_t stream) {
  (void)in_sizes; (void)n_in; (void)out_size; (void)ws_size;
  const float* in    = (const float*)d_in[0];
  const float* WUe   = (const float*)d_in[1];
  const float* ve    = (const float*)d_in[2];
  const float* Wih_e = (const float*)d_in[3];
  const float* Whh_e = (const float*)d_in[4];
  const float* bih_e = (const float*)d_in[5];
  const float* bhh_e = (const float*)d_in[6];
  const float* WUd   = (const float*)d_in[7];
  const float* vd    = (const float*)d_in[8];
  const float* wbt   = (const float*)d_in[9];
  const float* Wih_d = (const float*)d_in[10];
  const float* Whh_d = (const float*)d_in[11];
  const float* bih_d = (const float*)d_in[12];
  const float* bhh_d = (const float*)d_in[13];
  const float* WbW   = (const float*)d_in[14];
  const float* Wbb   = (const float*)d_in[15];
  const float* vbW   = (const float*)d_in[16];
  const float* vbb   = (const float*)d_in[17];
  float* ws  = (float*)d_ws;
  float* out = (float*)d_out;

  (void)hipFuncSetAttribute((const void*)darnn_main,
                            hipFuncAttributeMaxDynamicSharedMemorySize, SMEM_BYTES);
  hipLaunchKernelGGL(darnn_init, dim3(1024), dim3(256), 0, stream, ws, out);
  hipLaunchKernelGGL(darnn_main, dim3(256), dim3(512), SMEM_BYTES, stream,
                     in, WUe, ve, Wih_e, Whh_e, bih_e, bhh_e,
                     WUd, vd, wbt, Wih_d, Whh_d, bih_d, bhh_d,
                     WbW, Wbb, vbW, vbb, ws, out);
}

// Round 7
// 1195.291 us; speedup vs baseline: 1.6986x; 1.0116x over previous
//
#include <hip/hip_runtime.h>
#include <math.h>

// Problem dims: B=256, T=64, N=128, M=256, P=256, YD=1
// 256 blocks x 512 threads. Group = 16 blocks = 16 batches; block role mt = m-tile.
// Wave specialization: waves 0-3 attention || waves 4-7 h-GEMM, per step.
// R7 = R6 + FLAG-ARRAY BARRIERS: the central per-group counter (16 serialized
// agent-RMWs per barrier) is replaced by per-block flag words (own 64B line,
// plain sc1 stores, monotonic step values). Discovery: wave1 lanes 0-15 spin on
// the 16 flags (one wave-load polls all), then release the block via LDS flag
// F_TOP -- deletes the counter RMW queue and the discovery syncthreads.
// Encoder XA event likewise: FLB flags + F_XA LDS release (mid-barrier
// syncthreads deleted; safe -- each wave stages exactly the xah rows it reads).
// Flag accounting: FLA: encoder step t ends storing t+1 (-> 64); pre-decoder
// arrive stores 65; decoder step t waits >=65+t, ends storing 66+t (-> 128).
// F_TOP LDS targets: encoder t+1; decoder 65+t. FLB/F_XA: t+1 (encoder only).
// Flags live in the dead OFF_SDB region (zeroed by darnn_init each launch).

// Workspace layout (float offsets)
#define OFF_XWT   0u
#define OFF_XEWT  2097152u
#define OFF_XE    6291456u
#define OFF_HE    10485760u   // [2][16][256][16] h_e transposed [buf][grp][k][bl]
#define OFF_HD    10616832u
#define OFF_SB    10747904u   // yt channel only: parity-1 rows' slots 0,1
#define OFF_SDB   10780672u   // barrier flags: FLA/FLB per group (zero-init'd)
#define OFF_XA    10911744u   // [16][128][16]
#define OFF_CTX   10944512u
#define OFF_YT    11010048u   // (unused)
#define OFF_BAR   11010304u   // (unused in this rev)
#define WS_END    11010816u

#define SENT_U 0x7FC00001u

// LDS: SLAB | PER | SCR | FLG
#define SLAB_F 24576
#define PER_F  2432
#define SCR_F  12288
#define FLG_F  16
#define SMEM_F (SLAB_F + PER_F + SCR_F + FLG_F)
#define SMEM_BYTES (SMEM_F * 4)   // 157248 <= 160 KB

#define F_E   0
#define F_L   1
#define F_B   2
#define F_TOP 3
#define F_XA  4

__device__ __forceinline__ float fast_tanh(float x) {
  float xc = fminf(15.f, fmaxf(-15.f, x));
  float e = __expf(2.f * xc);
  return 1.f - 2.f * __builtin_amdgcn_rcpf(e + 1.f);
}
__device__ __forceinline__ float fast_sig(float x) {
  float xc = fminf(30.f, fmaxf(-30.f, x));
  return __builtin_amdgcn_rcpf(1.f + __expf(-xc));
}
__device__ __forceinline__ float wave_max(float v) {
#pragma unroll
  for (int o = 32; o; o >>= 1) v = fmaxf(v, __shfl_xor(v, o));
  return v;
}
__device__ __forceinline__ float wave_sum(float v) {
#pragma unroll
  for (int o = 32; o; o >>= 1) v += __shfl_xor(v, o);
  return v;
}
__device__ __forceinline__ float dot4(float4 a, float4 b) {
  return a.x*b.x + a.y*b.y + a.z*b.z + a.w*b.w;
}

// ---- device-scope (sc1) helpers; float4 only as ASM OUTPUT ----
__device__ __forceinline__ void st1_sc1(float* p, float v) {
  asm volatile("global_store_dword %0, %1, off sc1" :: "v"(p), "v"(v) : "memory");
}
__device__ __forceinline__ void stu_sc1(unsigned* p, unsigned v) {
  asm volatile("global_store_dword %0, %1, off sc1" :: "v"(p), "v"(v) : "memory");
}
__device__ __forceinline__ unsigned ldu_sc1(const unsigned* p) {
  unsigned v;
  asm volatile("global_load_dword %0, %1, off sc1\n\ts_waitcnt vmcnt(0)"
               : "=&v"(v) : "v"(p) : "memory");
  return v;
}
__device__ __forceinline__ void ld1q_sc1(float4& a, const float* pa) {
  asm volatile("global_load_dwordx4 %0, %1, off sc1\n\ts_waitcnt vmcnt(0)"
               : "=&v"(a) : "v"(pa) : "memory");
}
__device__ __forceinline__ void ld1q_nw(float4& a, const float* pa) {
  asm volatile("global_load_dwordx4 %0, %1, off sc1"
               : "=&v"(a) : "v"(pa) : "memory");
}
__device__ __forceinline__ void vm0() {
  asm volatile("s_waitcnt vmcnt(0)" ::: "memory");
}
__device__ __forceinline__ void lgk0() {
  asm volatile("s_waitcnt lgkmcnt(0)" ::: "memory");
}
__device__ __forceinline__ float ld1s_sc1(const float* p) {
  float v;
  asm volatile("global_load_dword %0, %1, off sc1\n\ts_waitcnt vmcnt(0)"
               : "=&v"(v) : "v"(p) : "memory");
  return v;
}
__device__ __forceinline__ void ld8s_sc1(
    float& a0,float& a1,float& a2,float& a3,float& a4,float& a5,float& a6,float& a7,
    const float* p0,const float* p1,const float* p2,const float* p3,
    const float* p4,const float* p5,const float* p6,const float* p7) {
  asm volatile(
      "global_load_dword %0, %8, off sc1\n\t"
      "global_load_dword %1, %9, off sc1\n\t"
      "global_load_dword %2, %10, off sc1\n\t"
      "global_load_dword %3, %11, off sc1\n\t"
      "global_load_dword %4, %12, off sc1\n\t"
      "global_load_dword %5, %13, off sc1\n\t"
      "global_load_dword %6, %14, off sc1\n\t"
      "global_load_dword %7, %15, off sc1\n\t"
      "s_waitcnt vmcnt(0)"
      : "=&v"(a0),"=&v"(a1),"=&v"(a2),"=&v"(a3),
        "=&v"(a4),"=&v"(a5),"=&v"(a6),"=&v"(a7)
      : "v"(p0),"v"(p1),"v"(p2),"v"(p3),"v"(p4),"v"(p5),"v"(p6),"v"(p7)
      : "memory");
}

// LDS flag sync (monotonic counters; subset-of-waves sync without s_barrier)
__device__ __forceinline__ void lds_inc(unsigned* f) {
  __hip_atomic_fetch_add(f, 1u, __ATOMIC_RELAXED, __HIP_MEMORY_SCOPE_WORKGROUP);
}
__device__ __forceinline__ void lds_poll(unsigned* f, unsigned tgt) {
  unsigned cur;
  do { cur = __hip_atomic_load(f, __ATOMIC_RELAXED, __HIP_MEMORY_SCOPE_WORKGROUP); } while (cur < tgt);
  asm volatile("" ::: "memory");
}

// Flag-array group barrier pieces.
// spin16: lanes holding idx 0-15 each spin on one flag word (64B apart).
__device__ __forceinline__ void spin16(const unsigned* fl, int idx, unsigned tgt) {
  const unsigned* p = fl + idx * 16;
  unsigned v = ldu_sc1(p);
  while (v < tgt) { __builtin_amdgcn_s_sleep(1); v = ldu_sc1(p); }
}
// one-time full barrier wait: tid<16 spin + syncthreads
__device__ __forceinline__ void wait_full(const unsigned* fl, unsigned tgt, int tid) {
  if (tid < 16) spin16(fl, tid, tgt);
  __syncthreads();
}

#define FMA16V(a0,a1,a2,a3,xv,wv) \
  a0.x += xv.x*wv.x; a0.y += xv.x*wv.y; a0.z += xv.x*wv.z; a0.w += xv.x*wv.w; \
  a1.x += xv.y*wv.x; a1.y += xv.y*wv.y; a1.z += xv.y*wv.z; a1.w += xv.y*wv.w; \
  a2.x += xv.z*wv.x; a2.y += xv.z*wv.y; a2.z += xv.z*wv.z; a2.w += xv.z*wv.w; \
  a3.x += xv.w*wv.x; a3.y += xv.w*wv.y; a3.z += xv.w*wv.z; a3.w += xv.w*wv.w;

__global__ void darnn_init(float* __restrict__ ws, float* __restrict__ out) {
  unsigned i = blockIdx.x * 256u + threadIdx.x;
  const unsigned span = WS_END - OFF_HE;
  for (unsigned idx = i; idx < span; idx += gridDim.x * 256u) ws[OFF_HE + idx] = 0.f;
  // zero EP[0] (encoder S-partials, parity 0) in each group's XeWt slice
  for (unsigned idx = i; idx < 262144u; idx += gridDim.x * 256u) {
    unsigned g = idx >> 14, off = idx & 16383u;
    ws[OFF_XEWT + g * 262144u + off] = 0.f;
  }
  if (i < 256u) out[i] = 0.f;
}

__global__ __launch_bounds__(512, 2) void darnn_main(
    const float* __restrict__ in,   const float* __restrict__ WUe,   const float* __restrict__ ve,
    const float* __restrict__ Wih_e,const float* __restrict__ Whh_e,
    const float* __restrict__ bih_e,const float* __restrict__ bhh_e,
    const float* __restrict__ WUd,  const float* __restrict__ vd,
    const float* __restrict__ wbt,  const float* __restrict__ Wih_d,
    const float* __restrict__ Whh_d,const float* __restrict__ bih_d, const float* __restrict__ bhh_d,
    const float* __restrict__ WbW,  const float* __restrict__ Wbb,
    const float* __restrict__ vbW,  const float* __restrict__ vbb,
    float* __restrict__ ws, float* __restrict__ out)
{
  extern __shared__ __align__(16) float sm[];
  float* SLAB = sm;
  float* PER  = sm + SLAB_F;
  float* SCR  = sm + SLAB_F + PER_F;
  unsigned* FLG = (unsigned*)(sm + SLAB_F + PER_F + SCR_F);
  const int tid = threadIdx.x;
  const int bid = blockIdx.x;
  const int grp = bid >> 4;
  const int mt  = bid & 15;
  const int b0  = grp << 4;
  const float SENTF = __uint_as_float(SENT_U);

  float* XWt  = ws + OFF_XWT;
  float* XeWt = ws + OFF_XEWT;
  float* Xe   = ws + OFF_XE;
  // partial-slot bases ([parity][bl][mt][j], j fastest)
  float* EP = ws + OFF_XEWT + (unsigned)grp * 262144u;  // [2][16][16][64]
  float* DP = ws + OFF_XWT  + (unsigned)grp * 131072u;  // [2][16][16][256]
  // flag arrays: per-block words, 64B apart; FLA = arrive, FLB = XA-ready
  unsigned* FLA = (unsigned*)(ws + OFF_SDB) + (unsigned)grp * 512u;
  unsigned* FLB = FLA + 256u;

  if (tid < FLG_F) FLG[tid] = 0u;

  // PER (encoder): wue_s [64][36]; ve_s @2304; bsum_e @2368
  float* wue_s  = PER;
  float* ve_s   = PER + 2304;
  float* bsum_e = PER + 2368;

  // rotated S-row for this thread's partial sweep (de-phases store bursts)
  const int jfixE = ((tid & 63) + mt * 4) & 63;

  // ---- one-time encoder staging ----
  {
    int r = tid & 63, kq = tid >> 6;
    int grow = (r & 3) * 256 + mt * 16 + (r >> 2);
#pragma unroll 4
    for (int q = 0; q < 12; ++q) {
      int k = kq * 48 + q * 4;
      float4 wv = (k < 128) ? *(const float4*)(Wih_e + grow * 128 + k)
                            : *(const float4*)(Whh_e + grow * 256 + (k - 128));
      SLAB[(k + 0) * 64 + r] = wv.x; SLAB[(k + 1) * 64 + r] = wv.y;
      SLAB[(k + 2) * 64 + r] = wv.z; SLAB[(k + 3) * 64 + r] = wv.w;
    }
    {
      int lin = tid * 4;
      int j = lin >> 5, c0 = lin & 31;
      int col = (c0 < 16) ? (mt * 16 + c0) : (256 + mt * 16 + (c0 - 16));
      float4 wv = *(const float4*)(WUe + j * 576 + col);
      *(float4*)(wue_s + j * 36 + c0) = wv;
    }
    if (tid < 64) {
      ve_s[tid] = ve[tid];
      int g = tid >> 4, m2 = tid & 15, m = mt * 16 + m2;
      bsum_e[tid] = bih_e[g * 256 + m] + bhh_e[g * 256 + m];
    }
  }

  // ---------------- P1: XWt[bid][j][n] = sum_k X[bid][k][n] * WU_e[j][512+k]
  {
    float* Xs = SCR;  // [128][68]
    const float* Xb = in + bid * 8256;
    __syncthreads();
    for (int it = 0; it < 16; ++it) {
      int lin = tid + it * 512;
      int k = lin >> 7, n = lin & 127;
      Xs[n * 68 + k] = Xb[k * 129 + n];
    }
    __syncthreads();
    int j = tid & 63, nh = tid >> 6;
    float acc[16];
#pragma unroll
    for (int i = 0; i < 16; ++i) acc[i] = 0.f;
    const float* wrow = WUe + j * 576 + 512;
    for (int kc = 0; kc < 4; ++kc) {
      float4 w0 = *(const float4*)(wrow + kc * 16 + 0);
      float4 w1 = *(const float4*)(wrow + kc * 16 + 4);
      float4 w2 = *(const float4*)(wrow + kc * 16 + 8);
      float4 w3 = *(const float4*)(wrow + kc * 16 + 12);
#pragma unroll
      for (int ni = 0; ni < 16; ++ni) {
        const float* xp = Xs + (nh * 16 + ni) * 68 + kc * 16;
        acc[ni] += dot4(*(const float4*)(xp + 0),  w0) + dot4(*(const float4*)(xp + 4),  w1)
                 + dot4(*(const float4*)(xp + 8),  w2) + dot4(*(const float4*)(xp + 12), w3);
      }
    }
    float* dst = XWt + bid * 8192 + j * 128 + nh * 16;
#pragma unroll
    for (int ni = 0; ni < 16; ++ni) dst[ni] = acc[ni];
    __syncthreads();
  }

  // hoist regs (constant over t); whc holds weights for ROTATED row jfixE
  float4 whc[8];
#pragma unroll
  for (int q = 0; q < 8; ++q) whc[q] = *(const float4*)(wue_s + jfixE * 36 + q * 4);
  float4 bsE = {0,0,0,0};
  {
    int m2 = tid & 15;
    bsE.x = bsum_e[m2]; bsE.y = bsum_e[16 + m2];
    bsE.z = bsum_e[32 + m2]; bsE.w = bsum_e[48 + m2];
  }
  // xwreg: wave w (0-3), lane l: n in {l, l+64}, j in w*16..+15
  float xwreg[32];
  if (tid < 256) {
    int w = tid >> 6, l = tid & 63;
    const float* xwp = XWt + bid * 8192;
#pragma unroll
    for (int jj = 0; jj < 16; ++jj) {
      xwreg[jj]      = xwp[(w * 16 + jj) * 128 + l];
      xwreg[16 + jj] = xwp[(w * 16 + jj) * 128 + 64 + l];
    }
  }
  float c_reg = 0.f;

  // ================ ENCODER: 64 steps ================
  for (int t = 0; t < 64; ++t) {
    const int rd = t & 1, wr2 = (t + 1) & 1;
    float* xah = SCR + 1024;     // [384][20]
    const int ks = tid >> 6, ml = (tid >> 2) & 15, b4 = tid & 3;
    float4 a0 = {0,0,0,0}, a1 = {0,0,0,0}, a2 = {0,0,0,0}, a3 = {0,0,0,0};

    // ---- top: wave1 discovers FLA >= t, releases block via F_TOP
    if (tid >= 64 && tid < 80) spin16(FLA, tid - 64, (unsigned)t);
    if (tid == 64) lds_inc(FLG + F_TOP);
    lds_poll(FLG + F_TOP, (unsigned)(t + 1));   // EP(rd), h(rd) visible

    if (tid < 256) {
      // ---- attention (waves 0-3); wave0 publishes XA then FLB flag
      int w = tid >> 6, l = tid & 63;
      float* Sj = SCR;           // [64]
      float* Ep = SCR + 64;      // [4][128]
      {  // gather S partials ([mt][j]): 1 float4/lane, shfl-reduce over mt (l>>2)
        float4 s;
        ld1q_sc1(s, EP + (unsigned)rd * 16384u + (unsigned)mt * 1024u
                       + (unsigned)((l >> 2) * 64 + w * 16 + (l & 3) * 4));
#pragma unroll
        for (int off = 4; off <= 32; off <<= 1) {
          s.x += __shfl_xor(s.x, off);
          s.y += __shfl_xor(s.y, off);
          s.z += __shfl_xor(s.z, off);
          s.w += __shfl_xor(s.w, off);
        }
        if (l < 4) *(float4*)(Sj + w * 16 + l * 4) = s;
        lgk0();
      }
      float e0 = 0.f, e1 = 0.f;
#pragma unroll
      for (int jj = 0; jj < 16; ++jj) {
        float s = Sj[w * 16 + jj];
        float vv = ve_s[w * 16 + jj];
        e0 += vv * fast_tanh(xwreg[jj] + s);
        e1 += vv * fast_tanh(xwreg[16 + jj] + s);
      }
      Ep[w * 128 + l] = e0;
      Ep[w * 128 + 64 + l] = e1;
      lgk0();
      if (l == 0) lds_inc(FLG + F_E);
      if (w == 0) {
        lds_poll(FLG + F_E, 4u * (t + 1));
        float En0 = Ep[l] + Ep[128 + l] + Ep[256 + l] + Ep[384 + l];
        float En1 = Ep[64 + l] + Ep[192 + l] + Ep[320 + l] + Ep[448 + l];
        float mx = wave_max(fmaxf(En0, En1));
        float ex0 = __expf(En0 - mx), ex1 = __expf(En1 - mx);
        float tot = wave_sum(ex0 + ex1);
        float rt = __builtin_amdgcn_rcpf(tot);
        float x0 = in[bid * 8256 + t * 129 + l];
        float x1 = in[bid * 8256 + t * 129 + 64 + l];
        float* XAg = ws + OFF_XA + (unsigned)grp * 2048;
        st1_sc1(XAg + l * 16 + mt, x0 * ex0 * rt);
        st1_sc1(XAg + (64 + l) * 16 + mt, x1 * ex1 * rt);
        vm0();
        if (tid == 0) stu_sc1(FLB + mt * 16, (unsigned)(t + 1));
      }
    } else {
      // ---- h-part GEMM (waves 4-7): k in [128,384)
      int u = tid - 256;
      float4 h0, h1, h2, h3;
      const float* hb = ws + OFF_HE + (unsigned)rd * 65536 + (unsigned)grp * 4096 + u * 16;
      ld1q_nw(h0, hb); ld1q_nw(h1, hb + 4); ld1q_nw(h2, hb + 8); ld1q_nw(h3, hb + 12);
      vm0();
      float* row = xah + (unsigned)(128 + u) * 20;
      *(float4*)(row + 0) = h0; *(float4*)(row + 4) = h1;
      *(float4*)(row + 8) = h2; *(float4*)(row + 12) = h3;
      lgk0();
      int s = u >> 6;
      const float* xp = xah + (unsigned)(128 + s * 64) * 20 + b4 * 4;
      const float* wp = SLAB + (unsigned)(128 + s * 64) * 64 + ml * 4;
#pragma unroll 8
      for (int kk = 0; kk < 64; ++kk) {
        float4 xv = *(const float4*)(xp + kk * 20);
        float4 wv = *(const float4*)(wp + kk * 64);
        FMA16V(a0, a1, a2, a3, xv, wv);
      }
    }

    // ---- mid: wave1 discovers all FLB >= t+1, releases via F_XA (no syncthreads;
    //      each wave stages exactly the xah rows it consumes -> no cross-wave LDS dep)
    if (tid >= 64 && tid < 80) spin16(FLB, tid - 64, (unsigned)(t + 1));
    if (tid == 64) lds_inc(FLG + F_XA);
    lds_poll(FLG + F_XA, (unsigned)(t + 1));

    // plant decoder yt-channel sentinels once (parity-1 slots 0,1); drains at arrive
    if (t == 63 && tid == 0) {
      float* sp = ws + OFF_SB + 16384u + (unsigned)bid * 64u;
      st1_sc1(sp + 0, SENTF); st1_sc1(sp + 1, SENTF);
    }
    {  // per-wave XA staging: wave ks stages exactly rows ks*16..+15 it consumes
      int l = tid & 63;
      int k = (ks << 4) + (l >> 2), i4 = (l & 3) * 4;
      float4 q;
      ld1q_sc1(q, ws + OFF_XA + (unsigned)grp * 2048 + k * 16 + i4);
      *(float4*)(xah + k * 20 + i4) = q;
      lgk0();                    // wave-local: no block sync needed
    }
    {  // x-part: 8 strips x 16 k
      const float* xp = xah + (unsigned)(ks * 16) * 20 + b4 * 4;
      const float* wp = SLAB + (unsigned)(ks * 16) * 64 + ml * 4;
#pragma unroll 8
      for (int kk = 0; kk < 16; ++kk) {
        float4 xv = *(const float4*)(xp + kk * 20);
        float4 wv = *(const float4*)(wp + kk * 64);
        FMA16V(a0, a1, a2, a3, xv, wv);
      }
    }
    __syncthreads();             // xah dead -> red
    float* red = SCR;            // [512][20]
    {
      float* rp = red + (unsigned)(ks * 64 + ml * 4 + b4) * 20;
      *(float4*)(rp + 0) = a0; *(float4*)(rp + 4) = a1;
      *(float4*)(rp + 8) = a2; *(float4*)(rp + 12) = a3;
    }
    __syncthreads();
    float* hcs = SCR + 10240;    // [16][32]
    if (tid < 256) {
      int m2 = tid & 15, bl = tid >> 4;
      int t2 = m2 * 4 + (bl >> 2), bs = bl & 3;
      float4 gate = {0,0,0,0};
#pragma unroll
      for (int k2 = 0; k2 < 8; ++k2) {
        float4 rr = *(const float4*)(red + (unsigned)(k2 * 64 + t2) * 20 + bs * 4);
        gate.x += rr.x; gate.y += rr.y; gate.z += rr.z; gate.w += rr.w;
      }
      float gi = gate.x + bsE.x, gf = gate.y + bsE.y;
      float gg = gate.z + bsE.z, go = gate.w + bsE.w;
      float cn = fast_sig(gf) * c_reg + fast_sig(gi) * fast_tanh(gg);
      float hn = fast_sig(go) * fast_tanh(cn);
      c_reg = cn;
      unsigned m = mt * 16 + m2;
      st1_sc1(ws + OFF_HE + (unsigned)wr2 * 65536 + (unsigned)grp * 4096 + m * 16 + bl, hn);
      st1_sc1(Xe + ((unsigned)(b0 + bl) * 64 + t) * 256 + m, hn);
      hcs[bl * 32 + m2] = hn;
      hcs[bl * 32 + 16 + m2] = cn;
    }
    __syncthreads();
    {  // S partial STORES: [bl][mt][j] layout -> wave stores 256B contiguous
      int wq = tid >> 6;
#pragma unroll
      for (int e2 = 0; e2 < 2; ++e2) {
        int bl2 = wq * 2 + e2;
        const float* hp = hcs + bl2 * 32;
        float s = 0.f;
#pragma unroll
        for (int q = 0; q < 4; ++q) {
          s += dot4(*(const float4*)(hp + q * 4), whc[q]);
          s += dot4(*(const float4*)(hp + 16 + q * 4), whc[4 + q]);
        }
        st1_sc1(EP + (unsigned)wr2 * 16384u + (unsigned)bl2 * 1024u
                   + (unsigned)mt * 64u + (unsigned)jfixE, s);
      }
    }
    // ---- arrive: drain all stores, then publish own FLA flag
    vm0();
    __syncthreads();
    if (tid == 0) stu_sc1(FLA + mt * 16, (unsigned)(t + 1));
  }
  wait_full(FLA, 64u, tid);      // all Xe published

  // ---- fill Xe row into regs: tid<256, m = tid, all 64 t
  float xe[64];
  if (tid < 256) {
    const float* xb = Xe + (unsigned)bid * 16384 + tid;
#pragma unroll
    for (int g8 = 0; g8 < 8; ++g8) {
      ld8s_sc1(xe[g8*8+0], xe[g8*8+1], xe[g8*8+2], xe[g8*8+3],
               xe[g8*8+4], xe[g8*8+5], xe[g8*8+6], xe[g8*8+7],
               xb + (g8*8+0)*256, xb + (g8*8+1)*256, xb + (g8*8+2)*256,
               xb + (g8*8+3)*256, xb + (g8*8+4)*256, xb + (g8*8+5)*256,
               xb + (g8*8+6)*256, xb + (g8*8+7)*256);
    }
  }

  // ---- decoder one-time staging ----
  float* vd_s   = PER;
  float* wbt_s  = PER + 256;
  float* bsum_d = PER + 520;
  float* wihd_s = PER + 584;
  float* q_s    = PER + 704;      // [64] q[t'] = sum_m wbt[1+m]*Xe[b][t'][m]
  float* qpart  = PER + 768;      // [4][64] scratch
  float* wudT   = SLAB + 16384;   // [32][256]
  const int jfixD = ((tid & 255) + mt * 16) & 255;
  __syncthreads();
  {
    int r = tid & 63, kq = tid >> 6;
    int grow = (r & 3) * 256 + mt * 16 + (r >> 2);
#pragma unroll 4
    for (int q = 0; q < 8; ++q) {
      int k = kq * 32 + q * 4;
      float4 wv = *(const float4*)(Whh_d + grow * 256 + k);
      SLAB[(k + 0) * 64 + r] = wv.x; SLAB[(k + 1) * 64 + r] = wv.y;
      SLAB[(k + 2) * 64 + r] = wv.z; SLAB[(k + 3) * 64 + r] = wv.w;
    }
    {
      int j = tid & 255, half = tid >> 8;
#pragma unroll
      for (int i = 0; i < 16; ++i) {
        int c = half * 16 + i;
        int col = (c < 16) ? (mt * 16 + c) : (256 + mt * 16 + (c - 16));
        wudT[c * 256 + j] = WUd[(unsigned)j * 768 + col];
      }
    }
    if (tid < 256) vd_s[tid] = vd[tid];
    if (tid < 257) wbt_s[tid] = wbt[tid];
    if (tid < 64) {
      int g = tid >> 4, m2 = tid & 15, m = mt * 16 + m2;
      bsum_d[tid] = bih_d[g * 256 + m] + bhh_d[g * 256 + m];
      wihd_s[tid] = Wih_d[g * 256 + m];
    }
  }
  __syncthreads();

  // ---- q precompute: q[t'] = sum_m wbt[1+m] * Xe[b][t'][m]  (one-time)
  if (tid < 256) {
    int w = tid >> 6, l = tid & 63;
    float wm = wbt_s[1 + tid];
#pragma unroll
    for (int t4 = 0; t4 < 64; ++t4) {
      float v = wave_sum(wm * xe[t4]);
      if (l == 0) qpart[w * 64 + t4] = v;
    }
  }
  __syncthreads();
  if (tid < 64) q_s[tid] = qpart[tid] + qpart[64 + tid] + qpart[128 + tid] + qpart[192 + tid];
  __syncthreads();

  // ---------------- P2: XeWt[bid][j][t'] = sum_k Xe[bid][t'][k] * WU_d[j][512+k]
  // (overwrites EP region — EP is dead after the encoder)
  {
    float* XeT = SCR;          // [64][64]
    float* Wdc = SCR + 4096;   // [64][128]
    int tt2 = tid & 15, jq = tid >> 4;
    for (int jc = 0; jc < 2; ++jc) {
      float4 c0 = {0,0,0,0}, c1 = {0,0,0,0}, c2 = {0,0,0,0}, c3 = {0,0,0,0};
      for (int kc = 0; kc < 4; ++kc) {
        __syncthreads();
        if (tid < 256 && (tid >> 6) == kc) {
          int kk = tid & 63;
#pragma unroll
          for (int t4 = 0; t4 < 16; ++t4) {
            float4 v = { xe[t4*4+0], xe[t4*4+1], xe[t4*4+2], xe[t4*4+3] };
            *(float4*)(XeT + kk * 64 + t4 * 4) = v;
          }
        }
        {
          int jj = tid >> 2, k16 = (tid & 3) * 16;
          const float* src = WUd + (unsigned)(jc * 128 + jj) * 768 + 512 + kc * 64 + k16;
#pragma unroll
          for (int s4 = 0; s4 < 4; ++s4) {
            float4 wv = *(const float4*)(src + s4 * 4);
            Wdc[(k16 + s4*4 + 0) * 128 + jj] = wv.x;
            Wdc[(k16 + s4*4 + 1) * 128 + jj] = wv.y;
            Wdc[(k16 + s4*4 + 2) * 128 + jj] = wv.z;
            Wdc[(k16 + s4*4 + 3) * 128 + jj] = wv.w;
          }
        }
        __syncthreads();
#pragma unroll 8
        for (int kk = 0; kk < 64; ++kk) {
          float4 xv = *(const float4*)(XeT + kk * 64 + tt2 * 4);
          float4 wv = *(const float4*)(Wdc + kk * 128 + jq * 4);
          FMA16V(c0, c1, c2, c3, wv, xv);
        }
      }
      int jb = jc * 128 + jq * 4;
      *(float4*)(XeWt + ((unsigned)bid * 256 + jb + 0) * 64 + tt2 * 4) = c0;
      *(float4*)(XeWt + ((unsigned)bid * 256 + jb + 1) * 64 + tt2 * 4) = c1;
      *(float4*)(XeWt + ((unsigned)bid * 256 + jb + 2) * 64 + tt2 * 4) = c2;
      *(float4*)(XeWt + ((unsigned)bid * 256 + jb + 3) * 64 + tt2 * 4) = c3;
    }
    __syncthreads();
  }

  // hoist decoder regs; wreg for ROTATED row jfixD
  float wreg[32];
#pragma unroll
  for (int c = 0; c < 32; ++c) wreg[c] = wudT[c * 256 + jfixD];
  float4 bsD = {0,0,0,0}, wiD = {0,0,0,0};
  {
    int m2 = tid & 15;
    bsD.x = bsum_d[m2]; bsD.y = bsum_d[16 + m2]; bsD.z = bsum_d[32 + m2]; bsD.w = bsum_d[48 + m2];
    wiD.x = wihd_s[m2]; wiD.y = wihd_s[16 + m2]; wiD.z = wihd_s[32 + m2]; wiD.w = wihd_s[48 + m2];
  }
  // xewreg: wave w (0-3), lane l = t': j in w*64..+63
  float xewreg[64];
  if (tid < 256) {
    int w = tid >> 6, l = tid & 63;
    const float* xew = XeWt + (unsigned)bid * 16384 + l;
#pragma unroll
    for (int jj = 0; jj < 64; ++jj) xewreg[jj] = xew[(w * 64 + jj) << 6];
  }
  // wave0 per-lane hoists: q[l] and y-input y_t for t=l (shfl'd per step)
  float q_reg = 0.f, yv = 0.f;
  if (tid < 64) {
    q_reg = q_s[tid];
    if (tid < 63) yv = in[bid * 8256 + tid * 129 + 128];
  }
  const float wbt0 = wbt_s[0];
  float cd_reg = 0.f;

  // ---- zero DP[0] (decoder S-partials, parity 0), own 4096-float slice,
  //      then arrive FLA=65 so step-0 consumers see the zeros.
  {
    float* dp0 = DP + (unsigned)mt * 4096u;
#pragma unroll
    for (int i8 = 0; i8 < 8; ++i8) st1_sc1(dp0 + (unsigned)(i8 * 512 + tid), 0.f);
    vm0();
    __syncthreads();
    if (tid == 0) stu_sc1(FLA + mt * 16, 65u);
  }

  // ================ DECODER: 63 steps ================
  // yt channel: slots 0/1 of SB parity-1 rows (sentineled at encoder t=63).
  // FLA: wait >= 65+t at top; store 66+t at tail. F_TOP target 65+t.
  for (int t = 0; t < 63; ++t) {
    const int rd = t & 1, wr2 = (t + 1) & 1;
    const int ml = (tid >> 2) & 15, b4 = tid & 3;
    float* hT  = SCR + 2048;     // [256][20]
    float* red = SCR + 7168;     // [256][20]

    // ---- top: wave1 discovers FLA >= 65+t, releases block via F_TOP
    if (tid >= 64 && tid < 80) spin16(FLA, tid - 64, (unsigned)(65 + t));
    if (tid == 64) lds_inc(FLG + F_TOP);
    lds_poll(FLG + F_TOP, (unsigned)(65 + t));  // DP(rd), h(rd), yt-refill visible

    if (tid < 256) {
      // ---- attention (waves 0-3); wave0 publishes yt right after softmax (q-trick)
      int w = tid >> 6, l = tid & 63;
      float* Sdj  = SCR;         // [256]
      float* lp   = SCR + 256;   // [4][64]
      float* beta = SCR + 512;   // [64] (t==62 only)
      {  // gather Sd partials ([mt][j]): 4x float4/lane + shfl-reduce over mt (l>>4)
        int jq = (l & 15) * 4, mq = l >> 4;
        const float* dpb = DP + (unsigned)rd * 65536u + (unsigned)mt * 4096u
                              + (unsigned)(w * 64 + jq);
        float4 p0, p1, p2, p3;
        ld1q_nw(p0, dpb + (unsigned)((mq +  0) * 256));
        ld1q_nw(p1, dpb + (unsigned)((mq +  4) * 256));
        ld1q_nw(p2, dpb + (unsigned)((mq +  8) * 256));
        ld1q_nw(p3, dpb + (unsigned)((mq + 12) * 256));
        vm0();
        float4 s;
        s.x = (p0.x + p1.x) + (p2.x + p3.x);
        s.y = (p0.y + p1.y) + (p2.y + p3.y);
        s.z = (p0.z + p1.z) + (p2.z + p3.z);
        s.w = (p0.w + p1.w) + (p2.w + p3.w);
#pragma unroll
        for (int off = 16; off <= 32; off <<= 1) {
          s.x += __shfl_xor(s.x, off);
          s.y += __shfl_xor(s.y, off);
          s.z += __shfl_xor(s.z, off);
          s.w += __shfl_xor(s.w, off);
        }
        if (mq == 0) *(float4*)(Sdj + w * 64 + jq) = s;
        lgk0();
      }
      float lpar = 0.f;
#pragma unroll 8
      for (int jj = 0; jj < 64; ++jj)
        lpar += vd_s[w * 64 + jj] * fast_tanh(xewreg[jj] + Sdj[w * 64 + jj]);
      lp[w * 64 + l] = lpar;
      lgk0();
      if (l == 0) lds_inc(FLG + F_L);
      if (w == 0) {
        lds_poll(FLG + F_L, 4u * (t + 1));
        float lv = lp[l] + lp[64 + l] + lp[128 + l] + lp[192 + l];
        float mx = wave_max(lv);
        float ex = __expf(lv - mx);
        float sw = wave_sum(ex);
        float rt = __builtin_amdgcn_rcpf(sw);
        float ytn = wave_sum(ex * q_reg);
        if (l == 0) {
          float yt = wbt0 * __shfl(yv, t) + ytn * rt;
          st1_sc1(ws + OFF_SB + 16384u + (unsigned)bid * 64u + (unsigned)rd, yt);
        }
        // fire-and-forget: consumers sentinel-poll; drain happens at arrive
        if (t == 62) {
          beta[l] = ex * rt;
          lgk0();
          if (l == 0) lds_inc(FLG + F_B);
        }
      }
      if (t == 62) {             // ctx only needed by FINAL
        lds_poll(FLG + F_B, 1u);
        lgk0();
        float ctx = 0.f;
#pragma unroll
        for (int tt = 0; tt < 64; ++tt) ctx += beta[tt] * xe[tt];
        st1_sc1(ws + OFF_CTX + (unsigned)bid * 256 + tid, ctx);
      }
    } else {
      // ---- full K=256 GEMM (waves 4-7) + red write
      if (tid == 256)            // sentinel-refill idle parity of own yt slot.
        st1_sc1(ws + OFF_SB + 16384u + (unsigned)bid * 64u + (unsigned)wr2, SENTF);
      int u = tid - 256;
      float4 h0, h1, h2, h3;
      const float* hb = ws + OFF_HD + (unsigned)rd * 65536 + (unsigned)grp * 4096 + u * 16;
      ld1q_nw(h0, hb); ld1q_nw(h1, hb + 4); ld1q_nw(h2, hb + 8); ld1q_nw(h3, hb + 12);
      vm0();
      float* row = hT + (unsigned)u * 20;
      *(float4*)(row + 0) = h0; *(float4*)(row + 4) = h1;
      *(float4*)(row + 8) = h2; *(float4*)(row + 12) = h3;
      lgk0();
      int s = u >> 6;
      float4 a0 = {0,0,0,0}, a1 = {0,0,0,0}, a2 = {0,0,0,0}, a3 = {0,0,0,0};
      const float* xp = hT + (unsigned)(s * 64) * 20 + b4 * 4;
      const float* wp = SLAB + (unsigned)(s * 64) * 64 + ml * 4;
#pragma unroll 8
      for (int kk = 0; kk < 64; ++kk) {
        float4 xv = *(const float4*)(xp + kk * 20);
        float4 wv = *(const float4*)(wp + kk * 64);
        FMA16V(a0, a1, a2, a3, xv, wv);
      }
      float* rp = red + (unsigned)(s * 64 + ml * 4 + b4) * 20;
      *(float4*)(rp + 0) = a0; *(float4*)(rp + 4) = a1;
      *(float4*)(rp + 8) = a2; *(float4*)(rp + 12) = a3;
    }
    __syncthreads();             // rejoin (red complete; attention scratch dead)

    float* hcs = SCR;            // [16][32] (attention scratch dead)
    if (tid < 256) {
      int m2 = tid & 15, bl = tid >> 4;
      int t2 = m2 * 4 + (bl >> 2), bs = bl & 3;
      float4 gate = {0,0,0,0};
#pragma unroll
      for (int k2 = 0; k2 < 4; ++k2) {
        float4 rr = *(const float4*)(red + (unsigned)(k2 * 64 + t2) * 20 + bs * 4);
        gate.x += rr.x; gate.y += rr.y; gate.z += rr.z; gate.w += rr.w;
      }
      const float* pyt = ws + OFF_SB + 16384u + (unsigned)(b0 + bl) * 64u + (unsigned)rd;
      float yt_reg = ld1s_sc1(pyt);
      while (__float_as_uint(yt_reg) == SENT_U) {
        __builtin_amdgcn_s_sleep(4);   // heavier backoff: retries are rare
        yt_reg = ld1s_sc1(pyt);
      }
      float gi = gate.x + yt_reg * wiD.x + bsD.x;
      float gf = gate.y + yt_reg * wiD.y + bsD.y;
      float gg = gate.z + yt_reg * wiD.z + bsD.z;
      float go = gate.w + yt_reg * wiD.w + bsD.w;
      float cn = fast_sig(gf) * cd_reg + fast_sig(gi) * fast_tanh(gg);
      float hn = fast_sig(go) * fast_tanh(cn);
      cd_reg = cn;
      unsigned m = mt * 16 + m2;
      st1_sc1(ws + OFF_HD + (unsigned)wr2 * 65536 + (unsigned)grp * 4096 + m * 16 + bl, hn);
      hcs[bl * 32 + m2] = hn;
      hcs[bl * 32 + 16 + m2] = cn;
    }
    __syncthreads();
    {  // Sd partial STORES: [bl][mt][j] layout -> wave stores 256B contiguous
      int half = tid >> 8;
#pragma unroll
      for (int e2 = 0; e2 < 8; ++e2) {
        int bl2 = half * 8 + e2;
        const float* hp = hcs + bl2 * 32;
        float s = 0.f;
#pragma unroll
        for (int c = 0; c < 16; ++c) s += hp[c] * wreg[c];
#pragma unroll
        for (int c = 0; c < 16; ++c) s += hp[16 + c] * wreg[16 + c];
        st1_sc1(DP + (unsigned)wr2 * 65536u + (unsigned)bl2 * 4096u
                   + (unsigned)mt * 256u + (unsigned)jfixD, s);
      }
    }
    // ---- arrive: drain all stores, then publish own FLA flag
    vm0();
    __syncthreads();
    if (tid == 0) stu_sc1(FLA + mt * 16, (unsigned)(66 + t));
  }
  wait_full(FLA, 128u, tid);     // h_d, ctx published

  // ---------------- FINAL
  {
    float* hsf  = SCR;          // [16][516]
    float* hid2 = SCR + 8256;   // [2][16][17]
    {
      int l0 = tid * 2, l1 = tid * 2 + 1;
      int k0 = l0 >> 2, i0 = l0 & 3, k1 = l1 >> 2, i1 = l1 & 3;
      const float* hb = ws + OFF_HD + 65536u + (unsigned)grp * 4096;
      int bl0 = l0 >> 6, c0 = (l0 & 63) * 4, bl1 = l1 >> 6, c1 = (l1 & 63) * 4;
      float4 qa, qb, qc, qd;
      ld1q_nw(qa, hb + k0 * 16 + i0 * 4);
      ld1q_nw(qb, hb + k1 * 16 + i1 * 4);
      ld1q_nw(qc, ws + OFF_CTX + (unsigned)(b0 + bl0) * 256 + c0);
      ld1q_nw(qd, ws + OFF_CTX + (unsigned)(b0 + bl1) * 256 + c1);
      vm0();
      hsf[(i0 * 4 + 0) * 516 + k0] = qa.x; hsf[(i0 * 4 + 1) * 516 + k0] = qa.y;
      hsf[(i0 * 4 + 2) * 516 + k0] = qa.z; hsf[(i0 * 4 + 3) * 516 + k0] = qa.w;
      hsf[(i1 * 4 + 0) * 516 + k1] = qb.x; hsf[(i1 * 4 + 1) * 516 + k1] = qb.y;
      hsf[(i1 * 4 + 2) * 516 + k1] = qb.z; hsf[(i1 * 4 + 3) * 516 + k1] = qb.w;
      *(float4*)(hsf + bl0 * 516 + 256 + c0) = qc;
      *(float4*)(hsf + bl1 * 516 + 256 + c1) = qd;
    }
    __syncthreads();
    int bl = tid & 15, p4 = (tid >> 4) & 15, half = tid >> 8;
    int row = mt * 16 + p4;
    const float* wrow = WbW + (unsigned)row * 512 + half * 256;
    const float* hp = hsf + bl * 516 + half * 256;
    float acc = half ? 0.f : Wbb[row];
#pragma unroll 8
    for (int q = 0; q < 64; ++q)
      acc += dot4(*(const float4*)(hp + q * 4), *(const float4*)(wrow + q * 4));
    hid2[half * 272 + bl * 17 + p4] = acc;
    __syncthreads();
    if (tid < 16) {
      float s = 0.f;
#pragma unroll
      for (int p = 0; p < 16; ++p)
        s += (hid2[tid * 17 + p] + hid2[272 + tid * 17 + p]) * vbW[mt * 16 + p];
      if (mt == 0) s += vbb[0];
      atomicAdd(&out[b0 + tid], s);
    }
  }
}

extern "C" void kernel_launch(void* const* d_in, const int* in_sizes, int n_in,
                              void* d_out, int out_size, void* d_ws, size_t ws_size,
                              hipStream_t stream) {
  (void)in_sizes; (void)n_in; (void)out_size; (void)ws_size;
  const float* in    = (const float*)d_in[0];
  const float* WUe   = (const float*)d_in[1];
  const float* ve    = (const float*)d_in[2];
  const float* Wih_e = (const float*)d_in[3];
  const float* Whh_e = (const float*)d_in[4];
  const float* bih_e = (const float*)d_in[5];
  const float* bhh_e = (const float*)d_in[6];
  const float* WUd   = (const float*)d_in[7];
  const float* vd    = (const float*)d_in[8];
  const float* wbt   = (const float*)d_in[9];
  const float* Wih_d = (const float*)d_in[10];
  const float* Whh_d = (const float*)d_in[11];
  const float* bih_d = (const float*)d_in[12];
  const float* bhh_d = (const float*)d_in[13];
  const float* WbW   = (const float*)d_in[14];
  const float* Wbb   = (const float*)d_in[15];
  const float* vbW   = (const float*)d_in[16];
  const float* vbb   = (const float*)d_in[17];
  float* ws  = (float*)d_ws;
  float* out = (float*)d_out;

  (void)hipFuncSetAttribute((const void*)darnn_main,
                            hipFuncAttributeMaxDynamicSharedMemorySize, SMEM_BYTES);
  hipLaunchKernelGGL(darnn_init, dim3(1024), dim3(256), 0, stream, ws, out);
  hipLaunchKernelGGL(darnn_main, dim3(256), dim3(512), SMEM_BYTES, stream,
                     in, WUe, ve, Wih_e, Whh_e, bih_e, bhh_e,
                     WUd, vd, wbt, Wih_d, Whh_d, bih_d, bhh_d,
                     WbW, Wbb, vbW, vbb, ws, out);
}

// Round 8
// 1190.054 us; speedup vs baseline: 1.7061x; 1.0044x over previous
//
#include <hip/hip_runtime.h>
#include <math.h>

// Problem dims: B=256, T=64, N=128, M=256, P=256, YD=1
// 256 blocks x 512 threads. Group = 16 blocks = 16 batches; block role mt = m-tile.
// Wave specialization: waves 0-3 attention || waves 4-7 h-GEMM, per step.
// R8 = R7 + two RT-path trims:
//  (1) Xe store deferral: Xe (encoder-output, consumed only post-encoder) is issued
//      LAST in the tail and drained with vmcnt(1) (in-order completion => HE+EP
//      guaranteed done; only Xe may remain in flight). Removes the slowest (HBM-
//      backed) store ack from the per-step arrive drain. t==63 uses full vm0 so
//      wait_full(64) covers all Xe. Waves 4-7 (no Xe) keep vm0.
//  (2) XA transposed to [mt][n]: producer wave0 writes two contiguous 256B
//      full-line bursts it exclusively owns (was: 128 partial-line 4B scatters
//      interleaved with 15 other blocks -> IC same-line write serialization on the
//      attention critical path). Consumers: 4x dword strided loads, same 1 RT.

// Workspace layout (float offsets)
#define OFF_XWT   0u
#define OFF_XEWT  2097152u
#define OFF_XE    6291456u
#define OFF_HE    10485760u   // [2][16][256][16] h_e transposed [buf][grp][k][bl]
#define OFF_HD    10616832u
#define OFF_SB    10747904u   // yt channel only: parity-1 rows' slots 0,1
#define OFF_SDB   10780672u   // barrier flags: FLA/FLB per group (zero-init'd)
#define OFF_XA    10911744u   // [16][16][128]  (grp, mt, n) -- transposed this rev
#define OFF_CTX   10944512u
#define OFF_YT    11010048u   // (unused)
#define OFF_BAR   11010304u   // (unused)
#define WS_END    11010816u

#define SENT_U 0x7FC00001u

// LDS: SLAB | PER | SCR | FLG
#define SLAB_F 24576
#define PER_F  2432
#define SCR_F  12288
#define FLG_F  16
#define SMEM_F (SLAB_F + PER_F + SCR_F + FLG_F)
#define SMEM_BYTES (SMEM_F * 4)   // 157248 <= 160 KB

#define F_E   0
#define F_L   1
#define F_B   2
#define F_TOP 3
#define F_XA  4

__device__ __forceinline__ float fast_tanh(float x) {
  float xc = fminf(15.f, fmaxf(-15.f, x));
  float e = __expf(2.f * xc);
  return 1.f - 2.f * __builtin_amdgcn_rcpf(e + 1.f);
}
__device__ __forceinline__ float fast_sig(float x) {
  float xc = fminf(30.f, fmaxf(-30.f, x));
  return __builtin_amdgcn_rcpf(1.f + __expf(-xc));
}
__device__ __forceinline__ float wave_max(float v) {
#pragma unroll
  for (int o = 32; o; o >>= 1) v = fmaxf(v, __shfl_xor(v, o));
  return v;
}
__device__ __forceinline__ float wave_sum(float v) {
#pragma unroll
  for (int o = 32; o; o >>= 1) v += __shfl_xor(v, o);
  return v;
}
__device__ __forceinline__ float dot4(float4 a, float4 b) {
  return a.x*b.x + a.y*b.y + a.z*b.z + a.w*b.w;
}

// ---- device-scope (sc1) helpers; float4 only as ASM OUTPUT ----
__device__ __forceinline__ void st1_sc1(float* p, float v) {
  asm volatile("global_store_dword %0, %1, off sc1" :: "v"(p), "v"(v) : "memory");
}
__device__ __forceinline__ void stu_sc1(unsigned* p, unsigned v) {
  asm volatile("global_store_dword %0, %1, off sc1" :: "v"(p), "v"(v) : "memory");
}
__device__ __forceinline__ unsigned ldu_sc1(const unsigned* p) {
  unsigned v;
  asm volatile("global_load_dword %0, %1, off sc1\n\ts_waitcnt vmcnt(0)"
               : "=&v"(v) : "v"(p) : "memory");
  return v;
}
__device__ __forceinline__ void ld1q_sc1(float4& a, const float* pa) {
  asm volatile("global_load_dwordx4 %0, %1, off sc1\n\ts_waitcnt vmcnt(0)"
               : "=&v"(a) : "v"(pa) : "memory");
}
__device__ __forceinline__ void ld1q_nw(float4& a, const float* pa) {
  asm volatile("global_load_dwordx4 %0, %1, off sc1"
               : "=&v"(a) : "v"(pa) : "memory");
}
__device__ __forceinline__ void vm0() {
  asm volatile("s_waitcnt vmcnt(0)" ::: "memory");
}
__device__ __forceinline__ void vm1() {
  asm volatile("s_waitcnt vmcnt(1)" ::: "memory");
}
__device__ __forceinline__ void lgk0() {
  asm volatile("s_waitcnt lgkmcnt(0)" ::: "memory");
}
__device__ __forceinline__ float ld1s_sc1(const float* p) {
  float v;
  asm volatile("global_load_dword %0, %1, off sc1\n\ts_waitcnt vmcnt(0)"
               : "=&v"(v) : "v"(p) : "memory");
  return v;
}
__device__ __forceinline__ void ld4s_sc1(
    float& a0,float& a1,float& a2,float& a3,
    const float* p0,const float* p1,const float* p2,const float* p3) {
  asm volatile(
      "global_load_dword %0, %4, off sc1\n\t"
      "global_load_dword %1, %5, off sc1\n\t"
      "global_load_dword %2, %6, off sc1\n\t"
      "global_load_dword %3, %7, off sc1\n\t"
      "s_waitcnt vmcnt(0)"
      : "=&v"(a0),"=&v"(a1),"=&v"(a2),"=&v"(a3)
      : "v"(p0),"v"(p1),"v"(p2),"v"(p3)
      : "memory");
}
__device__ __forceinline__ void ld8s_sc1(
    float& a0,float& a1,float& a2,float& a3,float& a4,float& a5,float& a6,float& a7,
    const float* p0,const float* p1,const float* p2,const float* p3,
    const float* p4,const float* p5,const float* p6,const float* p7) {
  asm volatile(
      "global_load_dword %0, %8, off sc1\n\t"
      "global_load_dword %1, %9, off sc1\n\t"
      "global_load_dword %2, %10, off sc1\n\t"
      "global_load_dword %3, %11, off sc1\n\t"
      "global_load_dword %4, %12, off sc1\n\t"
      "global_load_dword %5, %13, off sc1\n\t"
      "global_load_dword %6, %14, off sc1\n\t"
      "global_load_dword %7, %15, off sc1\n\t"
      "s_waitcnt vmcnt(0)"
      : "=&v"(a0),"=&v"(a1),"=&v"(a2),"=&v"(a3),
        "=&v"(a4),"=&v"(a5),"=&v"(a6),"=&v"(a7)
      : "v"(p0),"v"(p1),"v"(p2),"v"(p3),"v"(p4),"v"(p5),"v"(p6),"v"(p7)
      : "memory");
}

// LDS flag sync (monotonic counters; subset-of-waves sync without s_barrier)
__device__ __forceinline__ void lds_inc(unsigned* f) {
  __hip_atomic_fetch_add(f, 1u, __ATOMIC_RELAXED, __HIP_MEMORY_SCOPE_WORKGROUP);
}
__device__ __forceinline__ void lds_poll(unsigned* f, unsigned tgt) {
  unsigned cur;
  do { cur = __hip_atomic_load(f, __ATOMIC_RELAXED, __HIP_MEMORY_SCOPE_WORKGROUP); } while (cur < tgt);
  asm volatile("" ::: "memory");
}

// Flag-array group barrier pieces.
__device__ __forceinline__ void spin16(const unsigned* fl, int idx, unsigned tgt) {
  const unsigned* p = fl + idx * 16;
  unsigned v = ldu_sc1(p);
  while (v < tgt) { __builtin_amdgcn_s_sleep(1); v = ldu_sc1(p); }
}
__device__ __forceinline__ void wait_full(const unsigned* fl, unsigned tgt, int tid) {
  if (tid < 16) spin16(fl, tid, tgt);
  __syncthreads();
}

#define FMA16V(a0,a1,a2,a3,xv,wv) \
  a0.x += xv.x*wv.x; a0.y += xv.x*wv.y; a0.z += xv.x*wv.z; a0.w += xv.x*wv.w; \
  a1.x += xv.y*wv.x; a1.y += xv.y*wv.y; a1.z += xv.y*wv.z; a1.w += xv.y*wv.w; \
  a2.x += xv.z*wv.x; a2.y += xv.z*wv.y; a2.z += xv.z*wv.z; a2.w += xv.z*wv.w; \
  a3.x += xv.w*wv.x; a3.y += xv.w*wv.y; a3.z += xv.w*wv.z; a3.w += xv.w*wv.w;

__global__ void darnn_init(float* __restrict__ ws, float* __restrict__ out) {
  unsigned i = blockIdx.x * 256u + threadIdx.x;
  const unsigned span = WS_END - OFF_HE;
  for (unsigned idx = i; idx < span; idx += gridDim.x * 256u) ws[OFF_HE + idx] = 0.f;
  // zero EP[0] (encoder S-partials, parity 0) in each group's XeWt slice
  for (unsigned idx = i; idx < 262144u; idx += gridDim.x * 256u) {
    unsigned g = idx >> 14, off = idx & 16383u;
    ws[OFF_XEWT + g * 262144u + off] = 0.f;
  }
  if (i < 256u) out[i] = 0.f;
}

__global__ __launch_bounds__(512, 2) void darnn_main(
    const float* __restrict__ in,   const float* __restrict__ WUe,   const float* __restrict__ ve,
    const float* __restrict__ Wih_e,const float* __restrict__ Whh_e,
    const float* __restrict__ bih_e,const float* __restrict__ bhh_e,
    const float* __restrict__ WUd,  const float* __restrict__ vd,
    const float* __restrict__ wbt,  const float* __restrict__ Wih_d,
    const float* __restrict__ Whh_d,const float* __restrict__ bih_d, const float* __restrict__ bhh_d,
    const float* __restrict__ WbW,  const float* __restrict__ Wbb,
    const float* __restrict__ vbW,  const float* __restrict__ vbb,
    float* __restrict__ ws, float* __restrict__ out)
{
  extern __shared__ __align__(16) float sm[];
  float* SLAB = sm;
  float* PER  = sm + SLAB_F;
  float* SCR  = sm + SLAB_F + PER_F;
  unsigned* FLG = (unsigned*)(sm + SLAB_F + PER_F + SCR_F);
  const int tid = threadIdx.x;
  const int bid = blockIdx.x;
  const int grp = bid >> 4;
  const int mt  = bid & 15;
  const int b0  = grp << 4;
  const float SENTF = __uint_as_float(SENT_U);

  float* XWt  = ws + OFF_XWT;
  float* XeWt = ws + OFF_XEWT;
  float* Xe   = ws + OFF_XE;
  // partial-slot bases ([parity][bl][mt][j], j fastest)
  float* EP = ws + OFF_XEWT + (unsigned)grp * 262144u;  // [2][16][16][64]
  float* DP = ws + OFF_XWT  + (unsigned)grp * 131072u;  // [2][16][16][256]
  // flag arrays: per-block words, 64B apart; FLA = arrive, FLB = XA-ready
  unsigned* FLA = (unsigned*)(ws + OFF_SDB) + (unsigned)grp * 512u;
  unsigned* FLB = FLA + 256u;

  if (tid < FLG_F) FLG[tid] = 0u;

  // PER (encoder): wue_s [64][36]; ve_s @2304; bsum_e @2368
  float* wue_s  = PER;
  float* ve_s   = PER + 2304;
  float* bsum_e = PER + 2368;

  // rotated S-row for this thread's partial sweep (de-phases store bursts)
  const int jfixE = ((tid & 63) + mt * 4) & 63;

  // ---- one-time encoder staging ----
  {
    int r = tid & 63, kq = tid >> 6;
    int grow = (r & 3) * 256 + mt * 16 + (r >> 2);
#pragma unroll 4
    for (int q = 0; q < 12; ++q) {
      int k = kq * 48 + q * 4;
      float4 wv = (k < 128) ? *(const float4*)(Wih_e + grow * 128 + k)
                            : *(const float4*)(Whh_e + grow * 256 + (k - 128));
      SLAB[(k + 0) * 64 + r] = wv.x; SLAB[(k + 1) * 64 + r] = wv.y;
      SLAB[(k + 2) * 64 + r] = wv.z; SLAB[(k + 3) * 64 + r] = wv.w;
    }
    {
      int lin = tid * 4;
      int j = lin >> 5, c0 = lin & 31;
      int col = (c0 < 16) ? (mt * 16 + c0) : (256 + mt * 16 + (c0 - 16));
      float4 wv = *(const float4*)(WUe + j * 576 + col);
      *(float4*)(wue_s + j * 36 + c0) = wv;
    }
    if (tid < 64) {
      ve_s[tid] = ve[tid];
      int g = tid >> 4, m2 = tid & 15, m = mt * 16 + m2;
      bsum_e[tid] = bih_e[g * 256 + m] + bhh_e[g * 256 + m];
    }
  }

  // ---------------- P1: XWt[bid][j][n] = sum_k X[bid][k][n] * WU_e[j][512+k]
  {
    float* Xs = SCR;  // [128][68]
    const float* Xb = in + bid * 8256;
    __syncthreads();
    for (int it = 0; it < 16; ++it) {
      int lin = tid + it * 512;
      int k = lin >> 7, n = lin & 127;
      Xs[n * 68 + k] = Xb[k * 129 + n];
    }
    __syncthreads();
    int j = tid & 63, nh = tid >> 6;
    float acc[16];
#pragma unroll
    for (int i = 0; i < 16; ++i) acc[i] = 0.f;
    const float* wrow = WUe + j * 576 + 512;
    for (int kc = 0; kc < 4; ++kc) {
      float4 w0 = *(const float4*)(wrow + kc * 16 + 0);
      float4 w1 = *(const float4*)(wrow + kc * 16 + 4);
      float4 w2 = *(const float4*)(wrow + kc * 16 + 8);
      float4 w3 = *(const float4*)(wrow + kc * 16 + 12);
#pragma unroll
      for (int ni = 0; ni < 16; ++ni) {
        const float* xp = Xs + (nh * 16 + ni) * 68 + kc * 16;
        acc[ni] += dot4(*(const float4*)(xp + 0),  w0) + dot4(*(const float4*)(xp + 4),  w1)
                 + dot4(*(const float4*)(xp + 8),  w2) + dot4(*(const float4*)(xp + 12), w3);
      }
    }
    float* dst = XWt + bid * 8192 + j * 128 + nh * 16;
#pragma unroll
    for (int ni = 0; ni < 16; ++ni) dst[ni] = acc[ni];
    __syncthreads();
  }

  // hoist regs (constant over t); whc holds weights for ROTATED row jfixE
  float4 whc[8];
#pragma unroll
  for (int q = 0; q < 8; ++q) whc[q] = *(const float4*)(wue_s + jfixE * 36 + q * 4);
  float4 bsE = {0,0,0,0};
  {
    int m2 = tid & 15;
    bsE.x = bsum_e[m2]; bsE.y = bsum_e[16 + m2];
    bsE.z = bsum_e[32 + m2]; bsE.w = bsum_e[48 + m2];
  }
  // xwreg: wave w (0-3), lane l: n in {l, l+64}, j in w*16..+15
  float xwreg[32];
  if (tid < 256) {
    int w = tid >> 6, l = tid & 63;
    const float* xwp = XWt + bid * 8192;
#pragma unroll
    for (int jj = 0; jj < 16; ++jj) {
      xwreg[jj]      = xwp[(w * 16 + jj) * 128 + l];
      xwreg[16 + jj] = xwp[(w * 16 + jj) * 128 + 64 + l];
    }
  }
  float c_reg = 0.f;

  // ================ ENCODER: 64 steps ================
  for (int t = 0; t < 64; ++t) {
    const int rd = t & 1, wr2 = (t + 1) & 1;
    float* xah = SCR + 1024;     // [384][20]
    const int ks = tid >> 6, ml = (tid >> 2) & 15, b4 = tid & 3;
    float4 a0 = {0,0,0,0}, a1 = {0,0,0,0}, a2 = {0,0,0,0}, a3 = {0,0,0,0};

    // ---- top: wave1 discovers FLA >= t, releases block via F_TOP
    if (tid >= 64 && tid < 80) spin16(FLA, tid - 64, (unsigned)t);
    if (tid == 64) lds_inc(FLG + F_TOP);
    lds_poll(FLG + F_TOP, (unsigned)(t + 1));   // EP(rd), h(rd) visible

    if (tid < 256) {
      // ---- attention (waves 0-3); wave0 publishes XA then FLB flag
      int w = tid >> 6, l = tid & 63;
      float* Sj = SCR;           // [64]
      float* Ep = SCR + 64;      // [4][128]
      {  // gather S partials ([mt][j]): 1 float4/lane, shfl-reduce over mt (l>>2)
        float4 s;
        ld1q_sc1(s, EP + (unsigned)rd * 16384u + (unsigned)mt * 1024u
                       + (unsigned)((l >> 2) * 64 + w * 16 + (l & 3) * 4));
#pragma unroll
        for (int off = 4; off <= 32; off <<= 1) {
          s.x += __shfl_xor(s.x, off);
          s.y += __shfl_xor(s.y, off);
          s.z += __shfl_xor(s.z, off);
          s.w += __shfl_xor(s.w, off);
        }
        if (l < 4) *(float4*)(Sj + w * 16 + l * 4) = s;
        lgk0();
      }
      float e0 = 0.f, e1 = 0.f;
#pragma unroll
      for (int jj = 0; jj < 16; ++jj) {
        float s = Sj[w * 16 + jj];
        float vv = ve_s[w * 16 + jj];
        e0 += vv * fast_tanh(xwreg[jj] + s);
        e1 += vv * fast_tanh(xwreg[16 + jj] + s);
      }
      Ep[w * 128 + l] = e0;
      Ep[w * 128 + 64 + l] = e1;
      lgk0();
      if (l == 0) lds_inc(FLG + F_E);
      if (w == 0) {
        lds_poll(FLG + F_E, 4u * (t + 1));
        float En0 = Ep[l] + Ep[128 + l] + Ep[256 + l] + Ep[384 + l];
        float En1 = Ep[64 + l] + Ep[192 + l] + Ep[320 + l] + Ep[448 + l];
        float mx = wave_max(fmaxf(En0, En1));
        float ex0 = __expf(En0 - mx), ex1 = __expf(En1 - mx);
        float tot = wave_sum(ex0 + ex1);
        float rt = __builtin_amdgcn_rcpf(tot);
        float x0 = in[bid * 8256 + t * 129 + l];
        float x1 = in[bid * 8256 + t * 129 + 64 + l];
        // transposed XA: block mt's batch occupies [mt][0..127] -- 2x 256B full-line bursts
        float* XAg = ws + OFF_XA + (unsigned)grp * 2048u + (unsigned)mt * 128u;
        st1_sc1(XAg + l, x0 * ex0 * rt);
        st1_sc1(XAg + 64 + l, x1 * ex1 * rt);
        vm0();
        if (tid == 0) stu_sc1(FLB + mt * 16, (unsigned)(t + 1));
      }
    } else {
      // ---- h-part GEMM (waves 4-7): k in [128,384)
      int u = tid - 256;
      float4 h0, h1, h2, h3;
      const float* hb = ws + OFF_HE + (unsigned)rd * 65536 + (unsigned)grp * 4096 + u * 16;
      ld1q_nw(h0, hb); ld1q_nw(h1, hb + 4); ld1q_nw(h2, hb + 8); ld1q_nw(h3, hb + 12);
      vm0();
      float* row = xah + (unsigned)(128 + u) * 20;
      *(float4*)(row + 0) = h0; *(float4*)(row + 4) = h1;
      *(float4*)(row + 8) = h2; *(float4*)(row + 12) = h3;
      lgk0();
      int s = u >> 6;
      const float* xp = xah + (unsigned)(128 + s * 64) * 20 + b4 * 4;
      const float* wp = SLAB + (unsigned)(128 + s * 64) * 64 + ml * 4;
#pragma unroll 8
      for (int kk = 0; kk < 64; ++kk) {
        float4 xv = *(const float4*)(xp + kk * 20);
        float4 wv = *(const float4*)(wp + kk * 64);
        FMA16V(a0, a1, a2, a3, xv, wv);
      }
    }

    // ---- mid: wave1 discovers all FLB >= t+1, releases via F_XA
    if (tid >= 64 && tid < 80) spin16(FLB, tid - 64, (unsigned)(t + 1));
    if (tid == 64) lds_inc(FLG + F_XA);
    lds_poll(FLG + F_XA, (unsigned)(t + 1));

    // plant decoder yt-channel sentinels once (parity-1 slots 0,1); drains at arrive
    if (t == 63 && tid == 0) {
      float* sp = ws + OFF_SB + 16384u + (unsigned)bid * 64u;
      st1_sc1(sp + 0, SENTF); st1_sc1(sp + 1, SENTF);
    }
    {  // per-wave XA staging from transposed source: 4 dwords strided 512B
      int l = tid & 63;
      int k = (ks << 4) + (l >> 2), i4 = (l & 3) * 4;
      const float* xb2 = ws + OFF_XA + (unsigned)grp * 2048u + (unsigned)k;
      float v0, v1, v2, v3;
      ld4s_sc1(v0, v1, v2, v3,
               xb2 + (unsigned)((i4 + 0) * 128), xb2 + (unsigned)((i4 + 1) * 128),
               xb2 + (unsigned)((i4 + 2) * 128), xb2 + (unsigned)((i4 + 3) * 128));
      float* xd = xah + k * 20 + i4;
      xd[0] = v0; xd[1] = v1; xd[2] = v2; xd[3] = v3;
      lgk0();                    // wave-local: no block sync needed
    }
    {  // x-part: 8 strips x 16 k
      const float* xp = xah + (unsigned)(ks * 16) * 20 + b4 * 4;
      const float* wp = SLAB + (unsigned)(ks * 16) * 64 + ml * 4;
#pragma unroll 8
      for (int kk = 0; kk < 16; ++kk) {
        float4 xv = *(const float4*)(xp + kk * 20);
        float4 wv = *(const float4*)(wp + kk * 64);
        FMA16V(a0, a1, a2, a3, xv, wv);
      }
    }
    __syncthreads();             // xah dead -> red
    float* red = SCR;            // [512][20]
    {
      float* rp = red + (unsigned)(ks * 64 + ml * 4 + b4) * 20;
      *(float4*)(rp + 0) = a0; *(float4*)(rp + 4) = a1;
      *(float4*)(rp + 8) = a2; *(float4*)(rp + 12) = a3;
    }
    __syncthreads();
    float* hcs = SCR + 10240;    // [16][32]
    float hn_keep = 0.f;         // for deferred Xe store
    if (tid < 256) {
      int m2 = tid & 15, bl = tid >> 4;
      int t2 = m2 * 4 + (bl >> 2), bs = bl & 3;
      float4 gate = {0,0,0,0};
#pragma unroll
      for (int k2 = 0; k2 < 8; ++k2) {
        float4 rr = *(const float4*)(red + (unsigned)(k2 * 64 + t2) * 20 + bs * 4);
        gate.x += rr.x; gate.y += rr.y; gate.z += rr.z; gate.w += rr.w;
      }
      float gi = gate.x + bsE.x, gf = gate.y + bsE.y;
      float gg = gate.z + bsE.z, go = gate.w + bsE.w;
      float cn = fast_sig(gf) * c_reg + fast_sig(gi) * fast_tanh(gg);
      float hn = fast_sig(go) * fast_tanh(cn);
      c_reg = cn;
      hn_keep = hn;
      unsigned m = mt * 16 + m2;
      st1_sc1(ws + OFF_HE + (unsigned)wr2 * 65536 + (unsigned)grp * 4096 + m * 16 + bl, hn);
      hcs[bl * 32 + m2] = hn;
      hcs[bl * 32 + 16 + m2] = cn;
    }
    __syncthreads();
    {  // S partial STORES: [bl][mt][j] layout -> wave stores 256B contiguous
      int wq = tid >> 6;
#pragma unroll
      for (int e2 = 0; e2 < 2; ++e2) {
        int bl2 = wq * 2 + e2;
        const float* hp = hcs + bl2 * 32;
        float s = 0.f;
#pragma unroll
        for (int q = 0; q < 4; ++q) {
          s += dot4(*(const float4*)(hp + q * 4), whc[q]);
          s += dot4(*(const float4*)(hp + 16 + q * 4), whc[4 + q]);
        }
        st1_sc1(EP + (unsigned)wr2 * 16384u + (unsigned)bl2 * 1024u
                   + (unsigned)mt * 64u + (unsigned)jfixE, s);
      }
    }
    // ---- arrive: Xe issued LAST, drained lazily (vmcnt(1)); full vm0 at t==63.
    //      In-order completion => HE + EP stores are guaranteed done at vmcnt(1).
    if (tid < 256) {
      int m2 = tid & 15, bl = tid >> 4;
      unsigned m = mt * 16 + m2;
      st1_sc1(Xe + ((unsigned)(b0 + bl) * 64 + t) * 256 + m, hn_keep);
      if (t < 63) vm1(); else vm0();
    } else {
      vm0();
    }
    __syncthreads();
    if (tid == 0) stu_sc1(FLA + mt * 16, (unsigned)(t + 1));
  }
  wait_full(FLA, 64u, tid);      // all Xe published (step-63 used full vm0)

  // ---- fill Xe row into regs: tid<256, m = tid, all 64 t
  float xe[64];
  if (tid < 256) {
    const float* xb = Xe + (unsigned)bid * 16384 + tid;
#pragma unroll
    for (int g8 = 0; g8 < 8; ++g8) {
      ld8s_sc1(xe[g8*8+0], xe[g8*8+1], xe[g8*8+2], xe[g8*8+3],
               xe[g8*8+4], xe[g8*8+5], xe[g8*8+6], xe[g8*8+7],
               xb + (g8*8+0)*256, xb + (g8*8+1)*256, xb + (g8*8+2)*256,
               xb + (g8*8+3)*256, xb + (g8*8+4)*256, xb + (g8*8+5)*256,
               xb + (g8*8+6)*256, xb + (g8*8+7)*256);
    }
  }

  // ---- decoder one-time staging ----
  float* vd_s   = PER;
  float* wbt_s  = PER + 256;
  float* bsum_d = PER + 520;
  float* wihd_s = PER + 584;
  float* q_s    = PER + 704;      // [64] q[t'] = sum_m wbt[1+m]*Xe[b][t'][m]
  float* qpart  = PER + 768;      // [4][64] scratch
  float* wudT   = SLAB + 16384;   // [32][256]
  const int jfixD = ((tid & 255) + mt * 16) & 255;
  __syncthreads();
  {
    int r = tid & 63, kq = tid >> 6;
    int grow = (r & 3) * 256 + mt * 16 + (r >> 2);
#pragma unroll 4
    for (int q = 0; q < 8; ++q) {
      int k = kq * 32 + q * 4;
      float4 wv = *(const float4*)(Whh_d + grow * 256 + k);
      SLAB[(k + 0) * 64 + r] = wv.x; SLAB[(k + 1) * 64 + r] = wv.y;
      SLAB[(k + 2) * 64 + r] = wv.z; SLAB[(k + 3) * 64 + r] = wv.w;
    }
    {
      int j = tid & 255, half = tid >> 8;
#pragma unroll
      for (int i = 0; i < 16; ++i) {
        int c = half * 16 + i;
        int col = (c < 16) ? (mt * 16 + c) : (256 + mt * 16 + (c - 16));
        wudT[c * 256 + j] = WUd[(unsigned)j * 768 + col];
      }
    }
    if (tid < 256) vd_s[tid] = vd[tid];
    if (tid < 257) wbt_s[tid] = wbt[tid];
    if (tid < 64) {
      int g = tid >> 4, m2 = tid & 15, m = mt * 16 + m2;
      bsum_d[tid] = bih_d[g * 256 + m] + bhh_d[g * 256 + m];
      wihd_s[tid] = Wih_d[g * 256 + m];
    }
  }
  __syncthreads();

  // ---- q precompute: q[t'] = sum_m wbt[1+m] * Xe[b][t'][m]  (one-time)
  if (tid < 256) {
    int w = tid >> 6, l = tid & 63;
    float wm = wbt_s[1 + tid];
#pragma unroll
    for (int t4 = 0; t4 < 64; ++t4) {
      float v = wave_sum(wm * xe[t4]);
      if (l == 0) qpart[w * 64 + t4] = v;
    }
  }
  __syncthreads();
  if (tid < 64) q_s[tid] = qpart[tid] + qpart[64 + tid] + qpart[128 + tid] + qpart[192 + tid];
  __syncthreads();

  // ---------------- P2: XeWt[bid][j][t'] = sum_k Xe[bid][t'][k] * WU_d[j][512+k]
  // (overwrites EP region — EP is dead after the encoder)
  {
    float* XeT = SCR;          // [64][64]
    float* Wdc = SCR + 4096;   // [64][128]
    int tt2 = tid & 15, jq = tid >> 4;
    for (int jc = 0; jc < 2; ++jc) {
      float4 c0 = {0,0,0,0}, c1 = {0,0,0,0}, c2 = {0,0,0,0}, c3 = {0,0,0,0};
      for (int kc = 0; kc < 4; ++kc) {
        __syncthreads();
        if (tid < 256 && (tid >> 6) == kc) {
          int kk = tid & 63;
#pragma unroll
          for (int t4 = 0; t4 < 16; ++t4) {
            float4 v = { xe[t4*4+0], xe[t4*4+1], xe[t4*4+2], xe[t4*4+3] };
            *(float4*)(XeT + kk * 64 + t4 * 4) = v;
          }
        }
        {
          int jj = tid >> 2, k16 = (tid & 3) * 16;
          const float* src = WUd + (unsigned)(jc * 128 + jj) * 768 + 512 + kc * 64 + k16;
#pragma unroll
          for (int s4 = 0; s4 < 4; ++s4) {
            float4 wv = *(const float4*)(src + s4 * 4);
            Wdc[(k16 + s4*4 + 0) * 128 + jj] = wv.x;
            Wdc[(k16 + s4*4 + 1) * 128 + jj] = wv.y;
            Wdc[(k16 + s4*4 + 2) * 128 + jj] = wv.z;
            Wdc[(k16 + s4*4 + 3) * 128 + jj] = wv.w;
          }
        }
        __syncthreads();
#pragma unroll 8
        for (int kk = 0; kk < 64; ++kk) {
          float4 xv = *(const float4*)(XeT + kk * 64 + tt2 * 4);
          float4 wv = *(const float4*)(Wdc + kk * 128 + jq * 4);
          FMA16V(c0, c1, c2, c3, wv, xv);
        }
      }
      int jb = jc * 128 + jq * 4;
      *(float4*)(XeWt + ((unsigned)bid * 256 + jb + 0) * 64 + tt2 * 4) = c0;
      *(float4*)(XeWt + ((unsigned)bid * 256 + jb + 1) * 64 + tt2 * 4) = c1;
      *(float4*)(XeWt + ((unsigned)bid * 256 + jb + 2) * 64 + tt2 * 4) = c2;
      *(float4*)(XeWt + ((unsigned)bid * 256 + jb + 3) * 64 + tt2 * 4) = c3;
    }
    __syncthreads();
  }

  // hoist decoder regs; wreg for ROTATED row jfixD
  float wreg[32];
#pragma unroll
  for (int c = 0; c < 32; ++c) wreg[c] = wudT[c * 256 + jfixD];
  float4 bsD = {0,0,0,0}, wiD = {0,0,0,0};
  {
    int m2 = tid & 15;
    bsD.x = bsum_d[m2]; bsD.y = bsum_d[16 + m2]; bsD.z = bsum_d[32 + m2]; bsD.w = bsum_d[48 + m2];
    wiD.x = wihd_s[m2]; wiD.y = wihd_s[16 + m2]; wiD.z = wihd_s[32 + m2]; wiD.w = wihd_s[48 + m2];
  }
  // xewreg: wave w (0-3), lane l = t': j in w*64..+63
  float xewreg[64];
  if (tid < 256) {
    int w = tid >> 6, l = tid & 63;
    const float* xew = XeWt + (unsigned)bid * 16384 + l;
#pragma unroll
    for (int jj = 0; jj < 64; ++jj) xewreg[jj] = xew[(w * 64 + jj) << 6];
  }
  // wave0 per-lane hoists: q[l] and y-input y_t for t=l (shfl'd per step)
  float q_reg = 0.f, yv = 0.f;
  if (tid < 64) {
    q_reg = q_s[tid];
    if (tid < 63) yv = in[bid * 8256 + tid * 129 + 128];
  }
  const float wbt0 = wbt_s[0];
  float cd_reg = 0.f;

  // ---- zero DP[0] (decoder S-partials, parity 0), own 4096-float slice,
  //      then arrive FLA=65 so step-0 consumers see the zeros.
  {
    float* dp0 = DP + (unsigned)mt * 4096u;
#pragma unroll
    for (int i8 = 0; i8 < 8; ++i8) st1_sc1(dp0 + (unsigned)(i8 * 512 + tid), 0.f);
    vm0();
    __syncthreads();
    if (tid == 0) stu_sc1(FLA + mt * 16, 65u);
  }

  // ================ DECODER: 63 steps ================
  // yt channel: slots 0/1 of SB parity-1 rows (sentineled at encoder t=63).
  // FLA: wait >= 65+t at top; store 66+t at tail. F_TOP target 65+t.
  for (int t = 0; t < 63; ++t) {
    const int rd = t & 1, wr2 = (t + 1) & 1;
    const int ml = (tid >> 2) & 15, b4 = tid & 3;
    float* hT  = SCR + 2048;     // [256][20]
    float* red = SCR + 7168;     // [256][20]

    // ---- top: wave1 discovers FLA >= 65+t, releases block via F_TOP
    if (tid >= 64 && tid < 80) spin16(FLA, tid - 64, (unsigned)(65 + t));
    if (tid == 64) lds_inc(FLG + F_TOP);
    lds_poll(FLG + F_TOP, (unsigned)(65 + t));  // DP(rd), h(rd), yt-refill visible

    if (tid < 256) {
      // ---- attention (waves 0-3); wave0 publishes yt right after softmax (q-trick)
      int w = tid >> 6, l = tid & 63;
      float* Sdj  = SCR;         // [256]
      float* lp   = SCR + 256;   // [4][64]
      float* beta = SCR + 512;   // [64] (t==62 only)
      {  // gather Sd partials ([mt][j]): 4x float4/lane + shfl-reduce over mt (l>>4)
        int jq = (l & 15) * 4, mq = l >> 4;
        const float* dpb = DP + (unsigned)rd * 65536u + (unsigned)mt * 4096u
                              + (unsigned)(w * 64 + jq);
        float4 p0, p1, p2, p3;
        ld1q_nw(p0, dpb + (unsigned)((mq +  0) * 256));
        ld1q_nw(p1, dpb + (unsigned)((mq +  4) * 256));
        ld1q_nw(p2, dpb + (unsigned)((mq +  8) * 256));
        ld1q_nw(p3, dpb + (unsigned)((mq + 12) * 256));
        vm0();
        float4 s;
        s.x = (p0.x + p1.x) + (p2.x + p3.x);
        s.y = (p0.y + p1.y) + (p2.y + p3.y);
        s.z = (p0.z + p1.z) + (p2.z + p3.z);
        s.w = (p0.w + p1.w) + (p2.w + p3.w);
#pragma unroll
        for (int off = 16; off <= 32; off <<= 1) {
          s.x += __shfl_xor(s.x, off);
          s.y += __shfl_xor(s.y, off);
          s.z += __shfl_xor(s.z, off);
          s.w += __shfl_xor(s.w, off);
        }
        if (mq == 0) *(float4*)(Sdj + w * 64 + jq) = s;
        lgk0();
      }
      float lpar = 0.f;
#pragma unroll 8
      for (int jj = 0; jj < 64; ++jj)
        lpar += vd_s[w * 64 + jj] * fast_tanh(xewreg[jj] + Sdj[w * 64 + jj]);
      lp[w * 64 + l] = lpar;
      lgk0();
      if (l == 0) lds_inc(FLG + F_L);
      if (w == 0) {
        lds_poll(FLG + F_L, 4u * (t + 1));
        float lv = lp[l] + lp[64 + l] + lp[128 + l] + lp[192 + l];
        float mx = wave_max(lv);
        float ex = __expf(lv - mx);
        float sw = wave_sum(ex);
        float rt = __builtin_amdgcn_rcpf(sw);
        float ytn = wave_sum(ex * q_reg);
        if (l == 0) {
          float yt = wbt0 * __shfl(yv, t) + ytn * rt;
          st1_sc1(ws + OFF_SB + 16384u + (unsigned)bid * 64u + (unsigned)rd, yt);
        }
        // fire-and-forget: consumers sentinel-poll; drain happens at arrive
        if (t == 62) {
          beta[l] = ex * rt;
          lgk0();
          if (l == 0) lds_inc(FLG + F_B);
        }
      }
      if (t == 62) {             // ctx only needed by FINAL
        lds_poll(FLG + F_B, 1u);
        lgk0();
        float ctx = 0.f;
#pragma unroll
        for (int tt = 0; tt < 64; ++tt) ctx += beta[tt] * xe[tt];
        st1_sc1(ws + OFF_CTX + (unsigned)bid * 256 + tid, ctx);
      }
    } else {
      // ---- full K=256 GEMM (waves 4-7) + red write
      if (tid == 256)            // sentinel-refill idle parity of own yt slot.
        st1_sc1(ws + OFF_SB + 16384u + (unsigned)bid * 64u + (unsigned)wr2, SENTF);
      int u = tid - 256;
      float4 h0, h1, h2, h3;
      const float* hb = ws + OFF_HD + (unsigned)rd * 65536 + (unsigned)grp * 4096 + u * 16;
      ld1q_nw(h0, hb); ld1q_nw(h1, hb + 4); ld1q_nw(h2, hb + 8); ld1q_nw(h3, hb + 12);
      vm0();
      float* row = hT + (unsigned)u * 20;
      *(float4*)(row + 0) = h0; *(float4*)(row + 4) = h1;
      *(float4*)(row + 8) = h2; *(float4*)(row + 12) = h3;
      lgk0();
      int s = u >> 6;
      float4 a0 = {0,0,0,0}, a1 = {0,0,0,0}, a2 = {0,0,0,0}, a3 = {0,0,0,0};
      const float* xp = hT + (unsigned)(s * 64) * 20 + b4 * 4;
      const float* wp = SLAB + (unsigned)(s * 64) * 64 + ml * 4;
#pragma unroll 8
      for (int kk = 0; kk < 64; ++kk) {
        float4 xv = *(const float4*)(xp + kk * 20);
        float4 wv = *(const float4*)(wp + kk * 64);
        FMA16V(a0, a1, a2, a3, xv, wv);
      }
      float* rp = red + (unsigned)(s * 64 + ml * 4 + b4) * 20;
      *(float4*)(rp + 0) = a0; *(float4*)(rp + 4) = a1;
      *(float4*)(rp + 8) = a2; *(float4*)(rp + 12) = a3;
    }
    __syncthreads();             // rejoin (red complete; attention scratch dead)

    float* hcs = SCR;            // [16][32] (attention scratch dead)
    if (tid < 256) {
      int m2 = tid & 15, bl = tid >> 4;
      int t2 = m2 * 4 + (bl >> 2), bs = bl & 3;
      float4 gate = {0,0,0,0};
#pragma unroll
      for (int k2 = 0; k2 < 4; ++k2) {
        float4 rr = *(const float4*)(red + (unsigned)(k2 * 64 + t2) * 20 + bs * 4);
        gate.x += rr.x; gate.y += rr.y; gate.z += rr.z; gate.w += rr.w;
      }
      const float* pyt = ws + OFF_SB + 16384u + (unsigned)(b0 + bl) * 64u + (unsigned)rd;
      float yt_reg = ld1s_sc1(pyt);
      while (__float_as_uint(yt_reg) == SENT_U) {
        __builtin_amdgcn_s_sleep(4);   // heavier backoff: retries are rare
        yt_reg = ld1s_sc1(pyt);
      }
      float gi = gate.x + yt_reg * wiD.x + bsD.x;
      float gf = gate.y + yt_reg * wiD.y + bsD.y;
      float gg = gate.z + yt_reg * wiD.z + bsD.z;
      float go = gate.w + yt_reg * wiD.w + bsD.w;
      float cn = fast_sig(gf) * cd_reg + fast_sig(gi) * fast_tanh(gg);
      float hn = fast_sig(go) * fast_tanh(cn);
      cd_reg = cn;
      unsigned m = mt * 16 + m2;
      st1_sc1(ws + OFF_HD + (unsigned)wr2 * 65536 + (unsigned)grp * 4096 + m * 16 + bl, hn);
      hcs[bl * 32 + m2] = hn;
      hcs[bl * 32 + 16 + m2] = cn;
    }
    __syncthreads();
    {  // Sd partial STORES: [bl][mt][j] layout -> wave stores 256B contiguous
      int half = tid >> 8;
#pragma unroll
      for (int e2 = 0; e2 < 8; ++e2) {
        int bl2 = half * 8 + e2;
        const float* hp = hcs + bl2 * 32;
        float s = 0.f;
#pragma unroll
        for (int c = 0; c < 16; ++c) s += hp[c] * wreg[c];
#pragma unroll
        for (int c = 0; c < 16; ++c) s += hp[16 + c] * wreg[16 + c];
        st1_sc1(DP + (unsigned)wr2 * 65536u + (unsigned)bl2 * 4096u
                   + (unsigned)mt * 256u + (unsigned)jfixD, s);
      }
    }
    // ---- arrive: drain all stores, then publish own FLA flag
    vm0();
    __syncthreads();
    if (tid == 0) stu_sc1(FLA + mt * 16, (unsigned)(66 + t));
  }
  wait_full(FLA, 128u, tid);     // h_d, ctx published

  // ---------------- FINAL
  {
    float* hsf  = SCR;          // [16][516]
    float* hid2 = SCR + 8256;   // [2][16][17]
    {
      int l0 = tid * 2, l1 = tid * 2 + 1;
      int k0 = l0 >> 2, i0 = l0 & 3, k1 = l1 >> 2, i1 = l1 & 3;
      const float* hb = ws + OFF_HD + 65536u + (unsigned)grp * 4096;
      int bl0 = l0 >> 6, c0 = (l0 & 63) * 4, bl1 = l1 >> 6, c1 = (l1 & 63) * 4;
      float4 qa, qb, qc, qd;
      ld1q_nw(qa, hb + k0 * 16 + i0 * 4);
      ld1q_nw(qb, hb + k1 * 16 + i1 * 4);
      ld1q_nw(qc, ws + OFF_CTX + (unsigned)(b0 + bl0) * 256 + c0);
      ld1q_nw(qd, ws + OFF_CTX + (unsigned)(b0 + bl1) * 256 + c1);
      vm0();
      hsf[(i0 * 4 + 0) * 516 + k0] = qa.x; hsf[(i0 * 4 + 1) * 516 + k0] = qa.y;
      hsf[(i0 * 4 + 2) * 516 + k0] = qa.z; hsf[(i0 * 4 + 3) * 516 + k0] = qa.w;
      hsf[(i1 * 4 + 0) * 516 + k1] = qb.x; hsf[(i1 * 4 + 1) * 516 + k1] = qb.y;
      hsf[(i1 * 4 + 2) * 516 + k1] = qb.z; hsf[(i1 * 4 + 3) * 516 + k1] = qb.w;
      *(float4*)(hsf + bl0 * 516 + 256 + c0) = qc;
      *(float4*)(hsf + bl1 * 516 + 256 + c1) = qd;
    }
    __syncthreads();
    int bl = tid & 15, p4 = (tid >> 4) & 15, half = tid >> 8;
    int row = mt * 16 + p4;
    const float* wrow = WbW + (unsigned)row * 512 + half * 256;
    const float* hp = hsf + bl * 516 + half * 256;
    float acc = half ? 0.f : Wbb[row];
#pragma unroll 8
    for (int q = 0; q < 64; ++q)
      acc += dot4(*(const float4*)(hp + q * 4), *(const float4*)(wrow + q * 4));
    hid2[half * 272 + bl * 17 + p4] = acc;
    __syncthreads();
    if (tid < 16) {
      float s = 0.f;
#pragma unroll
      for (int p = 0; p < 16; ++p)
        s += (hid2[tid * 17 + p] + hid2[272 + tid * 17 + p]) * vbW[mt * 16 + p];
      if (mt == 0) s += vbb[0];
      atomicAdd(&out[b0 + tid], s);
    }
  }
}

extern "C" void kernel_launch(void* const* d_in, const int* in_sizes, int n_in,
                              void* d_out, int out_size, void* d_ws, size_t ws_size,
                              hipStream_t stream) {
  (void)in_sizes; (void)n_in; (void)out_size; (void)ws_size;
  const float* in    = (const float*)d_in[0];
  const float* WUe   = (const float*)d_in[1];
  const float* ve    = (const float*)d_in[2];
  const float* Wih_e = (const float*)d_in[3];
  const float* Whh_e = (const float*)d_in[4];
  const float* bih_e = (const float*)d_in[5];
  const float* bhh_e = (const float*)d_in[6];
  const float* WUd   = (const float*)d_in[7];
  const float* vd    = (const float*)d_in[8];
  const float* wbt   = (const float*)d_in[9];
  const float* Wih_d = (const float*)d_in[10];
  const float* Whh_d = (const float*)d_in[11];
  const float* bih_d = (const float*)d_in[12];
  const float* bhh_d = (const float*)d_in[13];
  const float* WbW   = (const float*)d_in[14];
  const float* Wbb   = (const float*)d_in[15];
  const float* vbW   = (const float*)d_in[16];
  const float* vbb   = (const float*)d_in[17];
  float* ws  = (float*)d_ws;
  float* out = (float*)d_out;

  (void)hipFuncSetAttribute((const void*)darnn_main,
                            hipFuncAttributeMaxDynamicSharedMemorySize, SMEM_BYTES);
  hipLaunchKernelGGL(darnn_init, dim3(1024), dim3(256), 0, stream, ws, out);
  hipLaunchKernelGGL(darnn_main, dim3(256), dim3(512), SMEM_BYTES, stream,
                     in, WUe, ve, Wih_e, Whh_e, bih_e, bhh_e,
                     WUd, vd, wbt, Wih_d, Whh_d, bih_d, bhh_d,
                     WbW, Wbb, vbW, vbb, ws, out);
}